// Round 1
// baseline (924.035 us; speedup 1.0000x reference)
//
#include <hip/hip_runtime.h>
#include <stdint.h>

typedef unsigned short u16;
typedef __bf16 bf16x8_t __attribute__((ext_vector_type(8)));
typedef float f32x4_t __attribute__((ext_vector_type(4)));

#define T_SEQ 2048
#define HID 4096
#define ROWQKV 6144

__device__ __forceinline__ float bf2f(u16 x){ return __uint_as_float(((uint32_t)x)<<16); }
__device__ __forceinline__ u16 f2bf(float f){
  uint32_t u = __float_as_uint(f);
  return (u16)((u + 0x7fffu + ((u>>16)&1u)) >> 16);
}

// ---------------- fp32 -> bf16 conversion (8 elems / thread) ----------------
__global__ void cvt_kernel(const float* __restrict__ src, u16* __restrict__ dst, int n8){
  int i = blockIdx.x*blockDim.x + threadIdx.x;
  if (i >= n8) return;
  const float4* s = (const float4*)src;
  float4 a = s[2*i], b = s[2*i+1];
  union { u16 u[8]; uint4 v; } o;
  o.u[0]=f2bf(a.x); o.u[1]=f2bf(a.y); o.u[2]=f2bf(a.z); o.u[3]=f2bf(a.w);
  o.u[4]=f2bf(b.x); o.u[5]=f2bf(b.y); o.u[6]=f2bf(b.z); o.u[7]=f2bf(b.w);
  ((uint4*)dst)[i] = o.v;
}

// ---------------- bias concat + rope tables ----------------
__global__ void setup_kernel(const float* __restrict__ bq, const float* __restrict__ bk,
                             const float* __restrict__ bv, const int* __restrict__ pos,
                             float* __restrict__ bqkv, float* __restrict__ cost,
                             float* __restrict__ sint){
  int i = blockIdx.x*blockDim.x + threadIdx.x;
  if (i < 6144) bqkv[i] = (i<4096) ? bq[i] : ((i<5120) ? bk[i-4096] : bv[i-5120]);
  if (i < T_SEQ*64){
    int t = i >> 6, d = i & 63;
    float inv = powf(10000.0f, -(float)(2*d) / 128.0f);
    float ang = (float)pos[t] * inv;
    cost[i] = cosf(ang);
    sint[i] = sinf(ang);
  }
}

// ---------------- GEMM: C[M,N] = A[M,K] * B[N,K]^T + bias ----------------
#define BM 128
#define BN 128
#define BK 32
#define LDK 40   // padded LDS row (elems): 80B stride -> ~2-way bank aliasing only

template<bool OUT_BF16>
__global__ __launch_bounds__(256)
void gemm_bt(const u16* __restrict__ A, const u16* __restrict__ B,
             const float* __restrict__ bias, u16* __restrict__ Cb,
             float* __restrict__ Cf, int K, int N)
{
  __shared__ u16 As[BM*LDK];
  __shared__ u16 Bs[BN*LDK];
  const int tid = threadIdx.x;
  const int lane = tid & 63;
  const int wid = tid >> 6;
  const int wr = (wid >> 1) * 64, wc = (wid & 1) * 64;
  const int bm = blockIdx.y * BM;
  const int bn = blockIdx.x * BN;
  const int l15 = lane & 15, l4 = lane >> 4;
  const int srow = tid >> 2;          // 0..63
  const int scol = (tid & 3) * 8;     // 0,8,16,24

  const u16* Ab = A + (size_t)(bm + srow)*K + scol;
  const u16* Bb = B + (size_t)(bn + srow)*K + scol;

  f32x4_t acc[4][4] = {};
  uint4 ra[2], rb[2];
  ra[0] = *(const uint4*)(Ab);
  ra[1] = *(const uint4*)(Ab + (size_t)64*K);
  rb[0] = *(const uint4*)(Bb);
  rb[1] = *(const uint4*)(Bb + (size_t)64*K);

  const int KT = K / BK;
  for (int kt = 0; kt < KT; ++kt){
    *(uint4*)&As[srow*LDK + scol]      = ra[0];
    *(uint4*)&As[(srow+64)*LDK + scol] = ra[1];
    *(uint4*)&Bs[srow*LDK + scol]      = rb[0];
    *(uint4*)&Bs[(srow+64)*LDK + scol] = rb[1];
    __syncthreads();
    if (kt + 1 < KT){
      const u16* An = Ab + (kt+1)*BK;
      const u16* Bn = Bb + (kt+1)*BK;
      ra[0] = *(const uint4*)(An);
      ra[1] = *(const uint4*)(An + (size_t)64*K);
      rb[0] = *(const uint4*)(Bn);
      rb[1] = *(const uint4*)(Bn + (size_t)64*K);
    }
    bf16x8_t af[4], bfr[4];
    #pragma unroll
    for (int m=0;m<4;m++)
      af[m] = *(const bf16x8_t*)&As[(wr + m*16 + l15)*LDK + l4*8];
    #pragma unroll
    for (int n=0;n<4;n++)
      bfr[n] = *(const bf16x8_t*)&Bs[(wc + n*16 + l15)*LDK + l4*8];
    #pragma unroll
    for (int m=0;m<4;m++){
      #pragma unroll
      for (int n=0;n<4;n++)
        acc[m][n] = __builtin_amdgcn_mfma_f32_16x16x32_bf16(af[m], bfr[n], acc[m][n], 0,0,0);
    }
    __syncthreads();
  }

  #pragma unroll
  for (int m=0;m<4;m++){
    #pragma unroll
    for (int n=0;n<4;n++){
      #pragma unroll
      for (int j=0;j<4;j++){
        int row = bm + wr + m*16 + l4*4 + j;
        int col = bn + wc + n*16 + l15;
        float v = acc[m][n][j] + bias[col];
        if constexpr (OUT_BF16) Cb[(size_t)row*N + col] = f2bf(v);
        else                    Cf[(size_t)row*N + col] = v;
      }
    }
  }
}

// ---------------- RoPE in-place on q (heads 0..31) and k (heads 32..39) ----------------
__global__ void rope_kernel(u16* __restrict__ qkv, const float* __restrict__ cost,
                            const float* __restrict__ sint){
  int i = blockIdx.x*blockDim.x + threadIdx.x;   // T*40*64 threads
  int t = i / 2560;
  int r = i % 2560;
  int h = r >> 6, d = r & 63;
  int base = (h < 32) ? h*128 : (4096 + (h-32)*128);
  size_t p1 = (size_t)t*ROWQKV + base + d;
  float x1 = bf2f(qkv[p1]), x2 = bf2f(qkv[p1+64]);
  float c = cost[(t<<6)+d], s = sint[(t<<6)+d];
  qkv[p1]    = f2bf(x1*c - x2*s);
  qkv[p1+64] = f2bf(x2*c + x1*s);
}

// ---------------- flash attention: block = (head, 64-row q tile) ----------------
#define KLD 136   // 64 x 128 K tile, padded row
#define VLD 72    // 128 x 64 V^T tile, padded row
#define PLD 72    // 64 x 64 P tile, padded row

__global__ __launch_bounds__(256)
void attn_kernel(const u16* __restrict__ qkv, u16* __restrict__ attn_o)
{
  __shared__ u16 Ks[64*KLD];
  __shared__ u16 Vt[128*VLD];
  __shared__ u16 Ps[64*PLD];
  const int tid = threadIdx.x, lane = tid&63, wid = tid>>6;
  const int l15 = lane&15, l4 = lane>>4;
  const int h  = blockIdx.x & 31;
  const int qt = 31 - (blockIdx.x >> 5);       // heavy tiles first
  const int q0 = qt * 64;
  const int kvh = h >> 2;
  const u16* Qg = qkv + h*128;
  const u16* Kg = qkv + 4096 + kvh*128;
  const u16* Vg = qkv + 5120 + kvh*128;

  // persistent Q fragments: wave wid owns q rows q0+wid*16 .. +15
  bf16x8_t qf[4];
  {
    size_t qrow = (size_t)(q0 + wid*16 + l15);
    #pragma unroll
    for (int kk=0;kk<4;kk++)
      qf[kk] = *(const bf16x8_t*)(Qg + qrow*ROWQKV + kk*32 + l4*8);
  }
  float mrow[4] = {-1e30f,-1e30f,-1e30f,-1e30f};
  float lrow[4] = {0.f,0.f,0.f,0.f};
  f32x4_t oacc[8] = {};
  const float scale = 0.08838834764831845f;  // 1/sqrt(128)

  const int krow = tid >> 2, kd0 = (tid & 3) * 32;
  const int vkv  = tid & 63, vdb = (tid >> 6) * 32;

  for (int kt = 0; kt <= qt; ++kt){
    int kv0 = kt * 64;
    // stage K [64][128]
    {
      const u16* src = Kg + (size_t)(kv0 + krow)*ROWQKV + kd0;
      #pragma unroll
      for (int i=0;i<4;i++)
        *(uint4*)&Ks[krow*KLD + kd0 + i*8] = *(const uint4*)(src + i*8);
      // stage V transposed -> Vt [d][kv]
      const u16* vs = Vg + (size_t)(kv0 + vkv)*ROWQKV + vdb;
      #pragma unroll
      for (int i=0;i<4;i++){
        uint4 vv = *(const uint4*)(vs + i*8);
        const u16* pv = (const u16*)&vv;
        #pragma unroll
        for (int e=0;e<8;e++)
          Vt[(vdb + i*8 + e)*VLD + vkv] = pv[e];
      }
    }
    __syncthreads();

    // S = Q K^T  (wave: 16 q rows x 64 kv)
    f32x4_t sacc[4] = {};
    #pragma unroll
    for (int n=0;n<4;n++){
      #pragma unroll
      for (int kk=0;kk<4;kk++){
        bf16x8_t kf = *(const bf16x8_t*)&Ks[(n*16 + l15)*KLD + kk*32 + l4*8];
        sacc[n] = __builtin_amdgcn_mfma_f32_16x16x32_bf16(qf[kk], kf, sacc[n], 0,0,0);
      }
    }
    // mask + online softmax
    float sv[4][4];
    float pmax[4] = {-1e30f,-1e30f,-1e30f,-1e30f};
    bool diag = (kt == qt);
    #pragma unroll
    for (int n=0;n<4;n++){
      int kvcol = kv0 + n*16 + l15;
      #pragma unroll
      for (int j=0;j<4;j++){
        float s = sacc[n][j] * scale;
        int qrow = q0 + wid*16 + l4*4 + j;
        if (diag && kvcol > qrow) s = -1e30f;
        sv[n][j] = s;
        pmax[j] = fmaxf(pmax[j], s);
      }
    }
    #pragma unroll
    for (int off=1; off<16; off<<=1){
      #pragma unroll
      for (int j=0;j<4;j++)
        pmax[j] = fmaxf(pmax[j], __shfl_xor(pmax[j], off, 64));
    }
    float esc[4], rsum[4] = {0.f,0.f,0.f,0.f};
    #pragma unroll
    for (int j=0;j<4;j++){
      float mn = fmaxf(mrow[j], pmax[j]);
      esc[j] = __expf(mrow[j] - mn);
      mrow[j] = mn;
    }
    #pragma unroll
    for (int n=0;n<4;n++){
      #pragma unroll
      for (int j=0;j<4;j++){
        float p = __expf(sv[n][j] - mrow[j]);
        sv[n][j] = p;
        rsum[j] += p;
      }
    }
    #pragma unroll
    for (int off=1; off<16; off<<=1){
      #pragma unroll
      for (int j=0;j<4;j++)
        rsum[j] += __shfl_xor(rsum[j], off, 64);
    }
    #pragma unroll
    for (int j=0;j<4;j++) lrow[j] = lrow[j]*esc[j] + rsum[j];
    #pragma unroll
    for (int n=0;n<8;n++){
      #pragma unroll
      for (int j=0;j<4;j++) oacc[n][j] *= esc[j];
    }
    // P -> LDS (wave-private region), re-layout as A-operand
    #pragma unroll
    for (int n=0;n<4;n++){
      #pragma unroll
      for (int j=0;j<4;j++)
        Ps[(wid*16 + l4*4 + j)*PLD + n*16 + l15] = f2bf(sv[n][j]);
    }
    // O += P V
    #pragma unroll
    for (int kk=0;kk<2;kk++){
      bf16x8_t pf = *(const bf16x8_t*)&Ps[(wid*16 + l15)*PLD + kk*32 + l4*8];
      #pragma unroll
      for (int n=0;n<8;n++){
        bf16x8_t vf = *(const bf16x8_t*)&Vt[(n*16 + l15)*VLD + kk*32 + l4*8];
        oacc[n] = __builtin_amdgcn_mfma_f32_16x16x32_bf16(pf, vf, oacc[n], 0,0,0);
      }
    }
    __syncthreads();
  }

  #pragma unroll
  for (int n=0;n<8;n++){
    #pragma unroll
    for (int j=0;j<4;j++){
      int qrow = q0 + wid*16 + l4*4 + j;
      int col  = h*128 + n*16 + l15;
      attn_o[(size_t)qrow*HID + col] = f2bf(oacc[n][j] / lrow[j]);
    }
  }
}

// ---------------- launcher ----------------
extern "C" void kernel_launch(void* const* d_in, const int* in_sizes, int n_in,
                              void* d_out, int out_size, void* d_ws, size_t ws_size,
                              hipStream_t stream)
{
  const float* hs = (const float*)d_in[0];
  const int*  pos = (const int*)d_in[1];
  const float* Wq = (const float*)d_in[2];
  const float* bq = (const float*)d_in[3];
  const float* Wk = (const float*)d_in[4];
  const float* bk = (const float*)d_in[5];
  const float* Wv = (const float*)d_in[6];
  const float* bv = (const float*)d_in[7];
  const float* Wo = (const float*)d_in[8];
  const float* bo = (const float*)d_in[9];
  float* out = (float*)d_out;

  char* ws = (char*)d_ws;
  u16* hs_bf   = (u16*)ws;  ws += (size_t)2048*4096*2;
  u16* Wqkv_bf = (u16*)ws;  ws += (size_t)6144*4096*2;
  u16* Wo_bf   = (u16*)ws;  ws += (size_t)4096*4096*2;
  u16* qkv     = (u16*)ws;  ws += (size_t)2048*6144*2;
  u16* attn_b  = (u16*)ws;  ws += (size_t)2048*4096*2;
  float* bqkv  = (float*)ws; ws += (size_t)6144*4;
  float* cost  = (float*)ws; ws += (size_t)2048*64*4;
  float* sint  = (float*)ws; ws += (size_t)2048*64*4;

  // fp32 -> bf16
  {
    int n8 = 2048*4096/8;
    cvt_kernel<<<(n8+255)/256, 256, 0, stream>>>(hs, hs_bf, n8);
    n8 = 4096*4096/8;
    cvt_kernel<<<(n8+255)/256, 256, 0, stream>>>(Wq, Wqkv_bf, n8);
    n8 = 1024*4096/8;
    cvt_kernel<<<(n8+255)/256, 256, 0, stream>>>(Wk, Wqkv_bf + (size_t)4096*4096, n8);
    cvt_kernel<<<(n8+255)/256, 256, 0, stream>>>(Wv, Wqkv_bf + (size_t)5120*4096, n8);
    n8 = 4096*4096/8;
    cvt_kernel<<<(n8+255)/256, 256, 0, stream>>>(Wo, Wo_bf, n8);
  }
  setup_kernel<<<(T_SEQ*64 + 255)/256, 256, 0, stream>>>(bq, bk, bv, pos, bqkv, cost, sint);

  // QKV projection: [2048,6144]
  gemm_bt<true><<<dim3(6144/BN, 2048/BM), 256, 0, stream>>>(hs_bf, Wqkv_bf, bqkv, qkv, nullptr, 4096, 6144);
  // RoPE on q,k
  rope_kernel<<<(T_SEQ*40*64)/256, 256, 0, stream>>>(qkv, cost, sint);
  // attention
  attn_kernel<<<1024, 256, 0, stream>>>(qkv, attn_b);
  // output projection: [2048,4096] fp32 + bias
  gemm_bt<false><<<dim3(4096/BN, 2048/BM), 256, 0, stream>>>(attn_b, Wo_bf, bo, nullptr, out, 4096, 4096);
}

// Round 2
// 430.735 us; speedup vs baseline: 2.1453x; 2.1453x over previous
//
#include <hip/hip_runtime.h>
#include <stdint.h>

typedef unsigned short u16;
typedef __bf16 bf16x8_t __attribute__((ext_vector_type(8)));
typedef float f32x4_t __attribute__((ext_vector_type(4)));

#define T_SEQ 2048
#define HID 4096
#define ROWQKV 6144

__device__ __forceinline__ float bf2f(u16 x){ return __uint_as_float(((uint32_t)x)<<16); }
__device__ __forceinline__ u16 f2bf(float f){
  uint32_t u = __float_as_uint(f);
  return (u16)((u + 0x7fffu + ((u>>16)&1u)) >> 16);
}

__device__ __forceinline__ void gload16(const void* g, void* l){
  __builtin_amdgcn_global_load_lds(
      (const __attribute__((address_space(1))) uint32_t*)g,
      (__attribute__((address_space(3))) uint32_t*)l, 16, 0, 0);
}

// ---------------- fp32 -> bf16 conversion (8 elems / thread) ----------------
__global__ void cvt_kernel(const float* __restrict__ src, u16* __restrict__ dst, int n8){
  int i = blockIdx.x*blockDim.x + threadIdx.x;
  if (i >= n8) return;
  const float4* s = (const float4*)src;
  float4 a = s[2*i], b = s[2*i+1];
  union { u16 u[8]; uint4 v; } o;
  o.u[0]=f2bf(a.x); o.u[1]=f2bf(a.y); o.u[2]=f2bf(a.z); o.u[3]=f2bf(a.w);
  o.u[4]=f2bf(b.x); o.u[5]=f2bf(b.y); o.u[6]=f2bf(b.z); o.u[7]=f2bf(b.w);
  ((uint4*)dst)[i] = o.v;
}

// ---------------- bias concat + rope tables ----------------
__global__ void setup_kernel(const float* __restrict__ bq, const float* __restrict__ bk,
                             const float* __restrict__ bv, const int* __restrict__ pos,
                             float* __restrict__ bqkv, float* __restrict__ cost,
                             float* __restrict__ sint){
  int i = blockIdx.x*blockDim.x + threadIdx.x;
  if (i < 6144) bqkv[i] = (i<4096) ? bq[i] : ((i<5120) ? bk[i-4096] : bv[i-5120]);
  if (i < T_SEQ*64){
    int t = i >> 6, d = i & 63;
    float inv = powf(10000.0f, -(float)(2*d) / 128.0f);
    float ang = (float)pos[t] * inv;
    cost[i] = cosf(ang);
    sint[i] = sinf(ang);
  }
}

// ---------------- GEMM (m97 structure): C[M,N] = A[M,K]*B[N,K]^T + bias -----
// 128x128 tile, BK=32, linear LDS, global_load_lds width=16, 4 waves, 4x4 acc.
#define BM 128
#define BN 128
#define BK 32

template<bool OUT_BF16>
__global__ __launch_bounds__(256)
void gemm_lds(const u16* __restrict__ A, const u16* __restrict__ B,
              const float* __restrict__ bias, u16* __restrict__ Cb,
              float* __restrict__ Cf, int K, int N)
{
  __shared__ u16 As[BM*BK];   // 8 KB, linear [row][k]
  __shared__ u16 Bs[BN*BK];   // 8 KB
  const int tid = threadIdx.x, lane = tid & 63, wid = tid >> 6;
  const int l15 = lane & 15, l4 = lane >> 4;
  const int wr = (wid >> 1)*64, wc = (wid & 1)*64;
  const int bm = blockIdx.y*BM, bn = blockIdx.x*BN;

  // Staging: wave `wid` owns 2 consecutive 1KB chunks (16 LDS rows each) of A
  // and of B. Within a chunk: lane i -> row i/4, col elems (i&3)*8.
  // global_load_lds writes lds_base + lane*16 (wave-uniform base, linear dest).
  const int srow = lane >> 2;          // 0..15 within chunk
  const int scol = (lane & 3) * 8;
  const u16* Ag = A + (size_t)(bm + wid*32 + srow)*K + scol;
  const u16* Bg = B + (size_t)(bn + wid*32 + srow)*K + scol;
  u16* AsW = &As[wid*32*BK];           // wave-uniform (wid*2 chunks * 512 elems)
  u16* BsW = &Bs[wid*32*BK];
  const size_t rowskip = (size_t)16*K; // 16 global rows (next chunk)

  f32x4_t acc[4][4] = {};
  const int KT = K / BK;
  for (int kt = 0; kt < KT; ++kt){
    const u16* a0 = Ag + kt*BK;
    const u16* b0 = Bg + kt*BK;
    gload16(a0,           AsW);
    gload16(a0 + rowskip, AsW + 16*BK);
    gload16(b0,           BsW);
    gload16(b0 + rowskip, BsW + 16*BK);
    __syncthreads();

    bf16x8_t af[4], bfr[4];
    #pragma unroll
    for (int m=0;m<4;m++)
      af[m] = *(const bf16x8_t*)&As[(wr + m*16 + l15)*BK + l4*8];
    #pragma unroll
    for (int n=0;n<4;n++)
      bfr[n] = *(const bf16x8_t*)&Bs[(wc + n*16 + l15)*BK + l4*8];
    #pragma unroll
    for (int m=0;m<4;m++){
      #pragma unroll
      for (int n=0;n<4;n++)
        acc[m][n] = __builtin_amdgcn_mfma_f32_16x16x32_bf16(af[m], bfr[n], acc[m][n], 0,0,0);
    }
    __syncthreads();
  }

  #pragma unroll
  for (int m=0;m<4;m++){
    #pragma unroll
    for (int n=0;n<4;n++){
      #pragma unroll
      for (int j=0;j<4;j++){
        int row = bm + wr + m*16 + l4*4 + j;
        int col = bn + wc + n*16 + l15;
        float v = acc[m][n][j] + bias[col];
        if constexpr (OUT_BF16) Cb[(size_t)row*N + col] = f2bf(v);
        else                    Cf[(size_t)row*N + col] = v;
      }
    }
  }
}

// ---------------- RoPE in-place on q (heads 0..31) and k (heads 32..39) -----
__global__ void rope_kernel(u16* __restrict__ qkv, const float* __restrict__ cost,
                            const float* __restrict__ sint){
  int i = blockIdx.x*blockDim.x + threadIdx.x;   // T*40*64 threads
  int t = i / 2560;
  int r = i % 2560;
  int h = r >> 6, d = r & 63;
  int base = (h < 32) ? h*128 : (4096 + (h-32)*128);
  size_t p1 = (size_t)t*ROWQKV + base + d;
  float x1 = bf2f(qkv[p1]), x2 = bf2f(qkv[p1+64]);
  float c = cost[(t<<6)+d], s = sint[(t<<6)+d];
  qkv[p1]    = f2bf(x1*c - x2*s);
  qkv[p1+64] = f2bf(x2*c + x1*s);
}

// ---------------- flash attention: block = (head, 64-row q tile) ------------
#define KLD 136   // 64 x 128 K tile, padded row
#define VLD 72    // 128 x 64 V^T tile, padded row
#define PLD 72    // 64 x 64 P tile, padded row

__global__ __launch_bounds__(256)
void attn_kernel(const u16* __restrict__ qkv, u16* __restrict__ attn_o)
{
  __shared__ u16 Ks[64*KLD];
  __shared__ u16 Vt[128*VLD];
  __shared__ u16 Ps[64*PLD];
  const int tid = threadIdx.x, lane = tid&63, wid = tid>>6;
  const int l15 = lane&15, l4 = lane>>4;
  const int h  = blockIdx.x & 31;
  const int qt = 31 - (blockIdx.x >> 5);       // heavy tiles first
  const int q0 = qt * 64;
  const int kvh = h >> 2;
  const u16* Qg = qkv + h*128;
  const u16* Kg = qkv + 4096 + kvh*128;
  const u16* Vg = qkv + 5120 + kvh*128;

  bf16x8_t qf[4];
  {
    size_t qrow = (size_t)(q0 + wid*16 + l15);
    #pragma unroll
    for (int kk=0;kk<4;kk++)
      qf[kk] = *(const bf16x8_t*)(Qg + qrow*ROWQKV + kk*32 + l4*8);
  }
  float mrow[4] = {-1e30f,-1e30f,-1e30f,-1e30f};
  float lrow[4] = {0.f,0.f,0.f,0.f};
  f32x4_t oacc[8] = {};
  const float scale = 0.08838834764831845f;  // 1/sqrt(128)

  const int krow = tid >> 2, kd0 = (tid & 3) * 32;
  const int vkv  = tid & 63, vdb = (tid >> 6) * 32;

  for (int kt = 0; kt <= qt; ++kt){
    int kv0 = kt * 64;
    {
      const u16* src = Kg + (size_t)(kv0 + krow)*ROWQKV + kd0;
      #pragma unroll
      for (int i=0;i<4;i++)
        *(uint4*)&Ks[krow*KLD + kd0 + i*8] = *(const uint4*)(src + i*8);
      const u16* vs = Vg + (size_t)(kv0 + vkv)*ROWQKV + vdb;
      #pragma unroll
      for (int i=0;i<4;i++){
        uint4 vv = *(const uint4*)(vs + i*8);
        const u16* pv = (const u16*)&vv;
        #pragma unroll
        for (int e=0;e<8;e++)
          Vt[(vdb + i*8 + e)*VLD + vkv] = pv[e];
      }
    }
    __syncthreads();

    f32x4_t sacc[4] = {};
    #pragma unroll
    for (int n=0;n<4;n++){
      #pragma unroll
      for (int kk=0;kk<4;kk++){
        bf16x8_t kf = *(const bf16x8_t*)&Ks[(n*16 + l15)*KLD + kk*32 + l4*8];
        sacc[n] = __builtin_amdgcn_mfma_f32_16x16x32_bf16(qf[kk], kf, sacc[n], 0,0,0);
      }
    }
    float sv[4][4];
    float pmax[4] = {-1e30f,-1e30f,-1e30f,-1e30f};
    bool diag = (kt == qt);
    #pragma unroll
    for (int n=0;n<4;n++){
      int kvcol = kv0 + n*16 + l15;
      #pragma unroll
      for (int j=0;j<4;j++){
        float s = sacc[n][j] * scale;
        int qrow = q0 + wid*16 + l4*4 + j;
        if (diag && kvcol > qrow) s = -1e30f;
        sv[n][j] = s;
        pmax[j] = fmaxf(pmax[j], s);
      }
    }
    #pragma unroll
    for (int off=1; off<16; off<<=1){
      #pragma unroll
      for (int j=0;j<4;j++)
        pmax[j] = fmaxf(pmax[j], __shfl_xor(pmax[j], off, 64));
    }
    float esc[4], rsum[4] = {0.f,0.f,0.f,0.f};
    #pragma unroll
    for (int j=0;j<4;j++){
      float mn = fmaxf(mrow[j], pmax[j]);
      esc[j] = __expf(mrow[j] - mn);
      mrow[j] = mn;
    }
    #pragma unroll
    for (int n=0;n<4;n++){
      #pragma unroll
      for (int j=0;j<4;j++){
        float p = __expf(sv[n][j] - mrow[j]);
        sv[n][j] = p;
        rsum[j] += p;
      }
    }
    #pragma unroll
    for (int off=1; off<16; off<<=1){
      #pragma unroll
      for (int j=0;j<4;j++)
        rsum[j] += __shfl_xor(rsum[j], off, 64);
    }
    #pragma unroll
    for (int j=0;j<4;j++) lrow[j] = lrow[j]*esc[j] + rsum[j];
    #pragma unroll
    for (int n=0;n<8;n++){
      #pragma unroll
      for (int j=0;j<4;j++) oacc[n][j] *= esc[j];
    }
    #pragma unroll
    for (int n=0;n<4;n++){
      #pragma unroll
      for (int j=0;j<4;j++)
        Ps[(wid*16 + l4*4 + j)*PLD + n*16 + l15] = f2bf(sv[n][j]);
    }
    #pragma unroll
    for (int kk=0;kk<2;kk++){
      bf16x8_t pf = *(const bf16x8_t*)&Ps[(wid*16 + l15)*PLD + kk*32 + l4*8];
      #pragma unroll
      for (int n=0;n<8;n++){
        bf16x8_t vf = *(const bf16x8_t*)&Vt[(n*16 + l15)*VLD + kk*32 + l4*8];
        oacc[n] = __builtin_amdgcn_mfma_f32_16x16x32_bf16(pf, vf, oacc[n], 0,0,0);
      }
    }
    __syncthreads();
  }

  #pragma unroll
  for (int n=0;n<8;n++){
    #pragma unroll
    for (int j=0;j<4;j++){
      int qrow = q0 + wid*16 + l4*4 + j;
      int col  = h*128 + n*16 + l15;
      attn_o[(size_t)qrow*HID + col] = f2bf(oacc[n][j] / lrow[j]);
    }
  }
}

// ---------------- launcher ----------------
extern "C" void kernel_launch(void* const* d_in, const int* in_sizes, int n_in,
                              void* d_out, int out_size, void* d_ws, size_t ws_size,
                              hipStream_t stream)
{
  const float* hs = (const float*)d_in[0];
  const int*  pos = (const int*)d_in[1];
  const float* Wq = (const float*)d_in[2];
  const float* bq = (const float*)d_in[3];
  const float* Wk = (const float*)d_in[4];
  const float* bk = (const float*)d_in[5];
  const float* Wv = (const float*)d_in[6];
  const float* bv = (const float*)d_in[7];
  const float* Wo = (const float*)d_in[8];
  const float* bo = (const float*)d_in[9];
  float* out = (float*)d_out;

  char* ws = (char*)d_ws;
  u16* hs_bf   = (u16*)ws;  ws += (size_t)2048*4096*2;
  u16* Wqkv_bf = (u16*)ws;  ws += (size_t)6144*4096*2;
  u16* Wo_bf   = (u16*)ws;  ws += (size_t)4096*4096*2;
  u16* qkv     = (u16*)ws;  ws += (size_t)2048*6144*2;
  u16* attn_b  = (u16*)ws;  ws += (size_t)2048*4096*2;
  float* bqkv  = (float*)ws; ws += (size_t)6144*4;
  float* cost  = (float*)ws; ws += (size_t)2048*64*4;
  float* sint  = (float*)ws; ws += (size_t)2048*64*4;

  {
    int n8 = 2048*4096/8;
    cvt_kernel<<<(n8+255)/256, 256, 0, stream>>>(hs, hs_bf, n8);
    n8 = 4096*4096/8;
    cvt_kernel<<<(n8+255)/256, 256, 0, stream>>>(Wq, Wqkv_bf, n8);
    n8 = 1024*4096/8;
    cvt_kernel<<<(n8+255)/256, 256, 0, stream>>>(Wk, Wqkv_bf + (size_t)4096*4096, n8);
    cvt_kernel<<<(n8+255)/256, 256, 0, stream>>>(Wv, Wqkv_bf + (size_t)5120*4096, n8);
    n8 = 4096*4096/8;
    cvt_kernel<<<(n8+255)/256, 256, 0, stream>>>(Wo, Wo_bf, n8);
  }
  setup_kernel<<<(T_SEQ*64 + 255)/256, 256, 0, stream>>>(bq, bk, bv, pos, bqkv, cost, sint);

  // QKV projection: [2048,6144]
  gemm_lds<true><<<dim3(6144/BN, 2048/BM), 256, 0, stream>>>(hs_bf, Wqkv_bf, bqkv, qkv, nullptr, 4096, 6144);
  // RoPE on q,k
  rope_kernel<<<(T_SEQ*40*64)/256, 256, 0, stream>>>(qkv, cost, sint);
  // attention
  attn_kernel<<<1024, 256, 0, stream>>>(qkv, attn_b);
  // output projection: [2048,4096] fp32 + bias
  gemm_lds<false><<<dim3(4096/BN, 2048/BM), 256, 0, stream>>>(attn_b, Wo_bf, bo, nullptr, out, 4096, 4096);
}

// Round 6
// 408.953 us; speedup vs baseline: 2.2595x; 1.0533x over previous
//
#include <hip/hip_runtime.h>
#include <stdint.h>

typedef unsigned short u16;
typedef __bf16 bf16x8_t __attribute__((ext_vector_type(8)));
typedef float f32x4_t __attribute__((ext_vector_type(4)));

#define T_SEQ 2048
#define HID 4096
#define ROWQKV 6144

__device__ __forceinline__ float bf2f(u16 x){ return __uint_as_float(((uint32_t)x)<<16); }
__device__ __forceinline__ u16 f2bf(float f){
  uint32_t u = __float_as_uint(f);
  return (u16)((u + 0x7fffu + ((u>>16)&1u)) >> 16);
}

__device__ __forceinline__ void gload16(const void* g, void* l){
  __builtin_amdgcn_global_load_lds(
      (const __attribute__((address_space(1))) uint32_t*)g,
      (__attribute__((address_space(3))) uint32_t*)l, 16, 0, 0);
}

// ---------------- fp32 -> bf16 conversion (8 elems / thread) ----------------
__global__ void cvt_kernel(const float* __restrict__ src, u16* __restrict__ dst, int n8){
  int i = blockIdx.x*blockDim.x + threadIdx.x;
  if (i >= n8) return;
  const float4* s = (const float4*)src;
  float4 a = s[2*i], b = s[2*i+1];
  union { u16 u[8]; uint4 v; } o;
  o.u[0]=f2bf(a.x); o.u[1]=f2bf(a.y); o.u[2]=f2bf(a.z); o.u[3]=f2bf(a.w);
  o.u[4]=f2bf(b.x); o.u[5]=f2bf(b.y); o.u[6]=f2bf(b.z); o.u[7]=f2bf(b.w);
  ((uint4*)dst)[i] = o.v;
}

// ---------------- bias concat + rope tables ----------------
__global__ void setup_kernel(const float* __restrict__ bq, const float* __restrict__ bk,
                             const float* __restrict__ bv, const int* __restrict__ pos,
                             float* __restrict__ bqkv, float* __restrict__ cost,
                             float* __restrict__ sint){
  int i = blockIdx.x*blockDim.x + threadIdx.x;
  if (i < 6144) bqkv[i] = (i<4096) ? bq[i] : ((i<5120) ? bk[i-4096] : bv[i-5120]);
  if (i < T_SEQ*64){
    int t = i >> 6, d = i & 63;
    float inv = powf(10000.0f, -(float)(2*d) / 128.0f);
    float ang = (float)pos[t] * inv;
    cost[i] = cosf(ang);
    sint[i] = sinf(ang);
  }
}

// ---------------- GEMM (m97 structure): C[M,N] = A[M,K]*B[N,K]^T + bias -----
#define BM 128
#define BN 128
#define BK 32

template<bool OUT_BF16>
__global__ __launch_bounds__(256)
void gemm_lds(const u16* __restrict__ A, const u16* __restrict__ B,
              const float* __restrict__ bias, u16* __restrict__ Cb,
              float* __restrict__ Cf, int K, int N)
{
  __shared__ u16 As[BM*BK];
  __shared__ u16 Bs[BN*BK];
  const int tid = threadIdx.x, lane = tid & 63, wid = tid >> 6;
  const int l15 = lane & 15, l4 = lane >> 4;
  const int wr = (wid >> 1)*64, wc = (wid & 1)*64;
  const int bm = blockIdx.y*BM, bn = blockIdx.x*BN;

  const int srow = lane >> 2;
  const int scol = (lane & 3) * 8;
  const u16* Ag = A + (size_t)(bm + wid*32 + srow)*K + scol;
  const u16* Bg = B + (size_t)(bn + wid*32 + srow)*K + scol;
  u16* AsW = &As[wid*32*BK];
  u16* BsW = &Bs[wid*32*BK];
  const size_t rowskip = (size_t)16*K;

  f32x4_t acc[4][4] = {};
  const int KT = K / BK;
  for (int kt = 0; kt < KT; ++kt){
    const u16* a0 = Ag + kt*BK;
    const u16* b0 = Bg + kt*BK;
    gload16(a0,           AsW);
    gload16(a0 + rowskip, AsW + 16*BK);
    gload16(b0,           BsW);
    gload16(b0 + rowskip, BsW + 16*BK);
    __syncthreads();

    bf16x8_t af[4], bfr[4];
    #pragma unroll
    for (int m=0;m<4;m++)
      af[m] = *(const bf16x8_t*)&As[(wr + m*16 + l15)*BK + l4*8];
    #pragma unroll
    for (int n=0;n<4;n++)
      bfr[n] = *(const bf16x8_t*)&Bs[(wc + n*16 + l15)*BK + l4*8];
    #pragma unroll
    for (int m=0;m<4;m++){
      #pragma unroll
      for (int n=0;n<4;n++)
        acc[m][n] = __builtin_amdgcn_mfma_f32_16x16x32_bf16(af[m], bfr[n], acc[m][n], 0,0,0);
    }
    __syncthreads();
  }

  #pragma unroll
  for (int m=0;m<4;m++){
    #pragma unroll
    for (int n=0;n<4;n++){
      #pragma unroll
      for (int j=0;j<4;j++){
        int row = bm + wr + m*16 + l4*4 + j;
        int col = bn + wc + n*16 + l15;
        float v = acc[m][n][j] + bias[col];
        if constexpr (OUT_BF16) Cb[(size_t)row*N + col] = f2bf(v);
        else                    Cf[(size_t)row*N + col] = v;
      }
    }
  }
}

// ---------------- RoPE in-place on q (heads 0..31) and k (heads 32..39) -----
__global__ void rope_kernel(u16* __restrict__ qkv, const float* __restrict__ cost,
                            const float* __restrict__ sint){
  int i = blockIdx.x*blockDim.x + threadIdx.x;
  int t = i / 2560;
  int r = i % 2560;
  int h = r >> 6, d = r & 63;
  int base = (h < 32) ? h*128 : (4096 + (h-32)*128);
  size_t p1 = (size_t)t*ROWQKV + base + d;
  float x1 = bf2f(qkv[p1]), x2 = bf2f(qkv[p1+64]);
  float c = cost[(t<<6)+d], s = sint[(t<<6)+d];
  qkv[p1]    = f2bf(x1*c - x2*s);
  qkv[p1+64] = f2bf(x2*c + x1*s);
}

// ---------------- flash attention: block = (head, 64-row q tile) ------------
#define KLD 136   // 64 x 128 K tile, padded row
#define VLD 72    // 128 x 64 V^T tile, padded row
#define PLD 72    // 64 x 64 P tile, padded row

__global__ __launch_bounds__(256)
void attn_kernel(const u16* __restrict__ qkv, u16* __restrict__ attn_o)
{
  __shared__ u16 Ks[64*KLD];
  __shared__ u16 Vt[128*VLD];
  __shared__ u16 Ps[64*PLD];
  const int tid = threadIdx.x, lane = tid&63, wid = tid>>6;
  const int l15 = lane&15, l4 = lane>>4;
  const int h  = blockIdx.x & 31;
  const int qt = 31 - (blockIdx.x >> 5);       // heavy tiles first
  const int q0 = qt * 64;
  const int kvh = h >> 2;
  const u16* Qg = qkv + h*128;
  const u16* Kg = qkv + 4096 + kvh*128;
  const u16* Vg = qkv + 5120 + kvh*128;

  bf16x8_t qf[4];
  {
    size_t qrow = (size_t)(q0 + wid*16 + l15);
    #pragma unroll
    for (int kk=0;kk<4;kk++)
      qf[kk] = *(const bf16x8_t*)(Qg + qrow*ROWQKV + kk*32 + l4*8);
  }
  float mrow[4] = {-1e30f,-1e30f,-1e30f,-1e30f};
  float lrow[4] = {0.f,0.f,0.f,0.f};
  f32x4_t oacc[8] = {};
  const float scale = 0.08838834764831845f;  // 1/sqrt(128)

  const int krow = tid >> 2, kd0 = (tid & 3) * 32;
  const int kvp  = tid & 31;          // kv pair (2*kvp, 2*kvp+1)
  const int vd0  = (tid >> 5) * 16;   // d range start

  for (int kt = 0; kt <= qt; ++kt){
    int kv0 = kt * 64;
    // stage K [64][128] (padded rows)
    {
      const u16* src = Kg + (size_t)(kv0 + krow)*ROWQKV + kd0;
      #pragma unroll
      for (int i=0;i<4;i++)
        *(uint4*)&Ks[krow*KLD + kd0 + i*8] = *(const uint4*)(src + i*8);
      // stage V transposed -> Vt[d][kv]: thread owns kv pair x 16 d values,
      // paired u32 writes (kv, kv+1 adjacent in row) -- vectorized vs scalar.
      const u16* va = Vg + (size_t)(kv0 + 2*kvp)*ROWQKV + vd0;
      uint4 r0 = *(const uint4*)va,            r1 = *(const uint4*)(va + 8);
      uint4 r2 = *(const uint4*)(va + ROWQKV), r3 = *(const uint4*)(va + ROWQKV + 8);
      const u16* ra = (const u16*)&r0; const u16* rb = (const u16*)&r2;
      #pragma unroll
      for (int e=0;e<8;e++)
        *(uint32_t*)&Vt[(vd0 + e)*VLD + 2*kvp] = (uint32_t)ra[e] | ((uint32_t)rb[e] << 16);
      ra = (const u16*)&r1; rb = (const u16*)&r3;
      #pragma unroll
      for (int e=0;e<8;e++)
        *(uint32_t*)&Vt[(vd0 + 8 + e)*VLD + 2*kvp] = (uint32_t)ra[e] | ((uint32_t)rb[e] << 16);
    }
    __syncthreads();

    f32x4_t sacc[4] = {};
    #pragma unroll
    for (int n=0;n<4;n++){
      #pragma unroll
      for (int kk=0;kk<4;kk++){
        bf16x8_t kf = *(const bf16x8_t*)&Ks[(n*16 + l15)*KLD + kk*32 + l4*8];
        sacc[n] = __builtin_amdgcn_mfma_f32_16x16x32_bf16(qf[kk], kf, sacc[n], 0,0,0);
      }
    }
    float sv[4][4];
    float pmax[4] = {-1e30f,-1e30f,-1e30f,-1e30f};
    bool diag = (kt == qt);
    #pragma unroll
    for (int n=0;n<4;n++){
      int kvcol = kv0 + n*16 + l15;
      #pragma unroll
      for (int j=0;j<4;j++){
        float s = sacc[n][j] * scale;
        int qrow = q0 + wid*16 + l4*4 + j;
        if (diag && kvcol > qrow) s = -1e30f;
        sv[n][j] = s;
        pmax[j] = fmaxf(pmax[j], s);
      }
    }
    #pragma unroll
    for (int off=1; off<16; off<<=1){
      #pragma unroll
      for (int j=0;j<4;j++)
        pmax[j] = fmaxf(pmax[j], __shfl_xor(pmax[j], off, 64));
    }
    float esc[4], rsum[4] = {0.f,0.f,0.f,0.f};
    #pragma unroll
    for (int j=0;j<4;j++){
      float mn = fmaxf(mrow[j], pmax[j]);
      esc[j] = __expf(mrow[j] - mn);
      mrow[j] = mn;
    }
    #pragma unroll
    for (int n=0;n<4;n++){
      #pragma unroll
      for (int j=0;j<4;j++){
        float p = __expf(sv[n][j] - mrow[j]);
        sv[n][j] = p;
        rsum[j] += p;
      }
    }
    #pragma unroll
    for (int off=1; off<16; off<<=1){
      #pragma unroll
      for (int j=0;j<4;j++)
        rsum[j] += __shfl_xor(rsum[j], off, 64);
    }
    #pragma unroll
    for (int j=0;j<4;j++) lrow[j] = lrow[j]*esc[j] + rsum[j];
    #pragma unroll
    for (int n=0;n<8;n++){
      #pragma unroll
      for (int j=0;j<4;j++) oacc[n][j] *= esc[j];
    }
    #pragma unroll
    for (int n=0;n<4;n++){
      #pragma unroll
      for (int j=0;j<4;j++)
        Ps[(wid*16 + l4*4 + j)*PLD + n*16 + l15] = f2bf(sv[n][j]);
    }
    #pragma unroll
    for (int kk=0;kk<2;kk++){
      bf16x8_t pf = *(const bf16x8_t*)&Ps[(wid*16 + l15)*PLD + kk*32 + l4*8];
      #pragma unroll
      for (int n=0;n<8;n++){
        bf16x8_t vf = *(const bf16x8_t*)&Vt[(n*16 + l15)*VLD + kk*32 + l4*8];
        oacc[n] = __builtin_amdgcn_mfma_f32_16x16x32_bf16(pf, vf, oacc[n], 0,0,0);
      }
    }
    __syncthreads();
  }

  #pragma unroll
  for (int n=0;n<8;n++){
    #pragma unroll
    for (int j=0;j<4;j++){
      int qrow = q0 + wid*16 + l4*4 + j;
      int col  = h*128 + n*16 + l15;
      attn_o[(size_t)qrow*HID + col] = f2bf(oacc[n][j] / lrow[j]);
    }
  }
}

// ---------------- launcher ----------------
extern "C" void kernel_launch(void* const* d_in, const int* in_sizes, int n_in,
                              void* d_out, int out_size, void* d_ws, size_t ws_size,
                              hipStream_t stream)
{
  const float* hs = (const float*)d_in[0];
  const int*  pos = (const int*)d_in[1];
  const float* Wq = (const float*)d_in[2];
  const float* bq = (const float*)d_in[3];
  const float* Wk = (const float*)d_in[4];
  const float* bk = (const float*)d_in[5];
  const float* Wv = (const float*)d_in[6];
  const float* bv = (const float*)d_in[7];
  const float* Wo = (const float*)d_in[8];
  const float* bo = (const float*)d_in[9];
  float* out = (float*)d_out;

  char* ws = (char*)d_ws;
  u16* hs_bf   = (u16*)ws;  ws += (size_t)2048*4096*2;
  u16* Wqkv_bf = (u16*)ws;  ws += (size_t)6144*4096*2;
  u16* Wo_bf   = (u16*)ws;  ws += (size_t)4096*4096*2;
  u16* qkv     = (u16*)ws;  ws += (size_t)2048*6144*2;
  u16* attn_b  = (u16*)ws;  ws += (size_t)2048*4096*2;
  float* bqkv  = (float*)ws; ws += (size_t)6144*4;
  float* cost  = (float*)ws; ws += (size_t)2048*64*4;
  float* sint  = (float*)ws; ws += (size_t)2048*64*4;

  {
    int n8 = 2048*4096/8;
    cvt_kernel<<<(n8+255)/256, 256, 0, stream>>>(hs, hs_bf, n8);
    n8 = 4096*4096/8;
    cvt_kernel<<<(n8+255)/256, 256, 0, stream>>>(Wq, Wqkv_bf, n8);
    n8 = 1024*4096/8;
    cvt_kernel<<<(n8+255)/256, 256, 0, stream>>>(Wk, Wqkv_bf + (size_t)4096*4096, n8);
    cvt_kernel<<<(n8+255)/256, 256, 0, stream>>>(Wv, Wqkv_bf + (size_t)5120*4096, n8);
    n8 = 4096*4096/8;
    cvt_kernel<<<(n8+255)/256, 256, 0, stream>>>(Wo, Wo_bf, n8);
  }
  setup_kernel<<<(T_SEQ*64 + 255)/256, 256, 0, stream>>>(bq, bk, bv, pos, bqkv, cost, sint);

  gemm_lds<true><<<dim3(6144/BN, 2048/BM), 256, 0, stream>>>(hs_bf, Wqkv_bf, bqkv, qkv, nullptr, 4096, 6144);
  rope_kernel<<<(T_SEQ*40*64)/256, 256, 0, stream>>>(qkv, cost, sint);
  attn_kernel<<<1024, 256, 0, stream>>>(qkv, attn_b);
  gemm_lds<false><<<dim3(4096/BN, 2048/BM), 256, 0, stream>>>(attn_b, Wo_bf, bo, nullptr, out, 4096, 4096);
}

// Round 7
// 402.826 us; speedup vs baseline: 2.2939x; 1.0152x over previous
//
#include <hip/hip_runtime.h>
#include <stdint.h>

typedef unsigned short u16;
typedef __bf16 bf16x8_t __attribute__((ext_vector_type(8)));
typedef float f32x4_t __attribute__((ext_vector_type(4)));

#define T_SEQ 2048
#define HID 4096
#define ROWQKV 6144

__device__ __forceinline__ float bf2f(u16 x){ return __uint_as_float(((uint32_t)x)<<16); }
__device__ __forceinline__ u16 f2bf(float f){
  uint32_t u = __float_as_uint(f);
  return (u16)((u + 0x7fffu + ((u>>16)&1u)) >> 16);
}

__device__ __forceinline__ void gload16(const void* g, void* l){
  __builtin_amdgcn_global_load_lds(
      (const __attribute__((address_space(1))) uint32_t*)g,
      (__attribute__((address_space(3))) uint32_t*)l, 16, 0, 0);
}

// ---------------- fp32 -> bf16 conversion (8 elems / thread) ----------------
__global__ void cvt_kernel(const float* __restrict__ src, u16* __restrict__ dst, int n8){
  int i = blockIdx.x*blockDim.x + threadIdx.x;
  if (i >= n8) return;
  const float4* s = (const float4*)src;
  float4 a = s[2*i], b = s[2*i+1];
  union { u16 u[8]; uint4 v; } o;
  o.u[0]=f2bf(a.x); o.u[1]=f2bf(a.y); o.u[2]=f2bf(a.z); o.u[3]=f2bf(a.w);
  o.u[4]=f2bf(b.x); o.u[5]=f2bf(b.y); o.u[6]=f2bf(b.z); o.u[7]=f2bf(b.w);
  ((uint4*)dst)[i] = o.v;
}

// ---------------- bias concat + rope tables ----------------
__global__ void setup_kernel(const float* __restrict__ bq, const float* __restrict__ bk,
                             const float* __restrict__ bv, const int* __restrict__ pos,
                             float* __restrict__ bqkv, float* __restrict__ cost,
                             float* __restrict__ sint){
  int i = blockIdx.x*blockDim.x + threadIdx.x;
  if (i < 6144) bqkv[i] = (i<4096) ? bq[i] : ((i<5120) ? bk[i-4096] : bv[i-5120]);
  if (i < T_SEQ*64){
    int t = i >> 6, d = i & 63;
    float inv = powf(10000.0f, -(float)(2*d) / 128.0f);
    float ang = (float)pos[t] * inv;
    cost[i] = cosf(ang);
    sint[i] = sinf(ang);
  }
}

// ------------- GEMM 8-phase (T3+T4+T5): C[M,N] = A[M,K]*B[N,K]^T + bias -----
// BM=128, BN=256, BK=64, 512 thr / 8 waves (2Mx4N), per-wave C = 64x64.
// LDS: 3 bufs x (A 128x64 + B 256x64) u16 = 3 x 24576 elems = 144 KB.
// Staging: tile t+2 staged during tile t (counted vmcnt(6), never 0 in loop).
// Swizzle: 16B-block col16 ^= (row&7), applied on global src AND ds_read addr.
#define BM8 128
#define BN8 256
#define BUFE 24576   // elems per buf

#define GBAR __builtin_amdgcn_s_barrier()
#define LGKM0 do{ asm volatile("s_waitcnt lgkmcnt(0)" ::: "memory"); \
                  __builtin_amdgcn_sched_barrier(0); }while(0)

#define AREAD(mq) do{ \
  const u16* ab = &lds[cur + abase + (mq)*2048]; \
  afr[0][0] = *(const bf16x8_t*)&ab[c0]; \
  afr[0][1] = *(const bf16x8_t*)&ab[c1]; \
  afr[1][0] = *(const bf16x8_t*)&ab[1024 + c0]; \
  afr[1][1] = *(const bf16x8_t*)&ab[1024 + c1]; }while(0)

#define BREAD(nq) do{ \
  const u16* bb = &lds[cur + bbase + (nq)*2048]; \
  bfr[0][0] = *(const bf16x8_t*)&bb[c0]; \
  bfr[0][1] = *(const bf16x8_t*)&bb[c1]; \
  bfr[1][0] = *(const bf16x8_t*)&bb[1024 + c0]; \
  bfr[1][1] = *(const bf16x8_t*)&bb[1024 + c1]; }while(0)

#define MM(mq,nq) do{ \
  acc[(mq)*2+0][(nq)*2+0] = __builtin_amdgcn_mfma_f32_16x16x32_bf16(afr[0][0], bfr[0][0], acc[(mq)*2+0][(nq)*2+0],0,0,0); \
  acc[(mq)*2+0][(nq)*2+1] = __builtin_amdgcn_mfma_f32_16x16x32_bf16(afr[0][0], bfr[1][0], acc[(mq)*2+0][(nq)*2+1],0,0,0); \
  acc[(mq)*2+1][(nq)*2+0] = __builtin_amdgcn_mfma_f32_16x16x32_bf16(afr[1][0], bfr[0][0], acc[(mq)*2+1][(nq)*2+0],0,0,0); \
  acc[(mq)*2+1][(nq)*2+1] = __builtin_amdgcn_mfma_f32_16x16x32_bf16(afr[1][0], bfr[1][0], acc[(mq)*2+1][(nq)*2+1],0,0,0); \
  acc[(mq)*2+0][(nq)*2+0] = __builtin_amdgcn_mfma_f32_16x16x32_bf16(afr[0][1], bfr[0][1], acc[(mq)*2+0][(nq)*2+0],0,0,0); \
  acc[(mq)*2+0][(nq)*2+1] = __builtin_amdgcn_mfma_f32_16x16x32_bf16(afr[0][1], bfr[1][1], acc[(mq)*2+0][(nq)*2+1],0,0,0); \
  acc[(mq)*2+1][(nq)*2+0] = __builtin_amdgcn_mfma_f32_16x16x32_bf16(afr[1][1], bfr[0][1], acc[(mq)*2+1][(nq)*2+0],0,0,0); \
  acc[(mq)*2+1][(nq)*2+1] = __builtin_amdgcn_mfma_f32_16x16x32_bf16(afr[1][1], bfr[1][1], acc[(mq)*2+1][(nq)*2+1],0,0,0); }while(0)

#define STAGE6(base) do{ \
  gload16(pA0,  &lds[(base) + w*1024]); \
  gload16(pA1,  &lds[(base) + w*1024 + 512]); \
  gload16(pB00, &lds[(base) + 8192  + w*1024]); \
  gload16(pB01, &lds[(base) + 8192  + w*1024 + 512]); \
  gload16(pB10, &lds[(base) + 16384 + w*1024]); \
  gload16(pB11, &lds[(base) + 16384 + w*1024 + 512]); }while(0)

#define ADV6 do{ pA0+=64; pA1+=64; pB00+=64; pB01+=64; pB10+=64; pB11+=64; }while(0)

template<bool OUT_BF16>
__global__ __launch_bounds__(512, 2)
void gemm_8p(const u16* __restrict__ A, const u16* __restrict__ B,
             const float* __restrict__ bias, u16* __restrict__ Cb,
             float* __restrict__ Cf, int K, int N)
{
  __shared__ u16 lds[3*BUFE];
  const int tid = threadIdx.x, lane = tid & 63, w = tid >> 6;
  const int l15 = lane & 15, l4 = lane >> 4;
  const int wm = w >> 2, wn = w & 3;

  // XCD-aware bijective block swizzle (grid % 8 == 0 for both call sites)
  const int nwg = gridDim.x * gridDim.y;
  int flat = blockIdx.y * gridDim.x + blockIdx.x;
  flat = (flat & 7) * (nwg >> 3) + (flat >> 3);
  const int bx = flat % gridDim.x, by = flat / gridDim.x;
  const int bm = by * BM8, bn = bx * BN8;

  // staging: wave w, load j -> 8 rows (w*16 + j*8 + srow), 16B block scol
  const int srow = lane >> 3;         // 0..7
  const int scol = lane & 7;          // 16B block
  const int swc  = (scol ^ srow) * 8; // pre-swizzled k-elem offset (both sides!)
  const int rA0 = w*16 + srow, rA1 = w*16 + 8 + srow;
  const u16* pA0  = A + (size_t)(bm + rA0)*K + swc;
  const u16* pA1  = A + (size_t)(bm + rA1)*K + swc;
  const u16* pB00 = B + (size_t)(bn + rA0)*K + swc;
  const u16* pB01 = B + (size_t)(bn + rA1)*K + swc;
  const u16* pB10 = B + (size_t)(bn + 128 + rA0)*K + swc;
  const u16* pB11 = B + (size_t)(bn + 128 + rA1)*K + swc;

  // fragment-read constants (swizzled 16B block on read side)
  const int fsw = l15 & 7;
  const int c0 = ((0 + l4) ^ fsw) * 8;   // kk=0
  const int c1 = ((4 + l4) ^ fsw) * 8;   // kk=1
  const int abase = (wm*64 + l15) * 64;
  const int bbase = 8192 + (wn >> 1)*8192 + ((wn & 1)*64 + l15) * 64;

  f32x4_t acc[4][4] = {};
  const int KT = K >> 6;

  // prologue: stage tiles 0 and 1
  STAGE6(0);     ADV6;
  STAGE6(BUFE);  ADV6;
  asm volatile("s_waitcnt vmcnt(6)" ::: "memory");
  GBAR;

  for (int t = 0; t < KT; ++t){
    const int cur = (t % 3) * BUFE;
    const int sb  = ((t + 2) % 3) * BUFE;
    const bool st = (t + 2 < KT);
    bf16x8_t afr[2][2], bfr[2][2];
    // phase 0: A-frags(mq0) + B-frags(nq0) | stage A unit of t+2
    AREAD(0); BREAD(0);
    if (st){ gload16(pA0, &lds[sb + w*1024]); gload16(pA1, &lds[sb + w*1024 + 512]); }
    GBAR; LGKM0;
    __builtin_amdgcn_s_setprio(1); MM(0,0); __builtin_amdgcn_s_setprio(0);
    GBAR;
    // phase 1: B-frags(nq1) | stage B0 unit
    BREAD(1);
    if (st){ gload16(pB00, &lds[sb + 8192 + w*1024]); gload16(pB01, &lds[sb + 8192 + w*1024 + 512]); }
    GBAR; LGKM0;
    __builtin_amdgcn_s_setprio(1); MM(0,1); __builtin_amdgcn_s_setprio(0);
    GBAR;
    // phase 2: A-frags(mq1) + B-frags(nq0) | stage B1 unit, advance ptrs
    AREAD(1); BREAD(0);
    if (st){ gload16(pB10, &lds[sb + 16384 + w*1024]); gload16(pB11, &lds[sb + 16384 + w*1024 + 512]); ADV6; }
    GBAR; LGKM0;
    __builtin_amdgcn_s_setprio(1); MM(1,0); __builtin_amdgcn_s_setprio(0);
    GBAR;
    // phase 3: B-frags(nq1) | counted vmcnt at tile end
    BREAD(1);
    GBAR; LGKM0;
    __builtin_amdgcn_s_setprio(1); MM(1,1); __builtin_amdgcn_s_setprio(0);
    if (st)                 asm volatile("s_waitcnt vmcnt(6)" ::: "memory");
    else if (t + 1 < KT)    asm volatile("s_waitcnt vmcnt(0)" ::: "memory");
    GBAR;
  }

  #pragma unroll
  for (int m=0;m<4;m++){
    #pragma unroll
    for (int n=0;n<4;n++){
      #pragma unroll
      for (int j=0;j<4;j++){
        int row = bm + wm*64 + m*16 + l4*4 + j;
        int col = bn + wn*64 + n*16 + l15;
        float v = acc[m][n][j] + bias[col];
        if constexpr (OUT_BF16) Cb[(size_t)row*N + col] = f2bf(v);
        else                    Cf[(size_t)row*N + col] = v;
      }
    }
  }
}

// ---------------- RoPE in-place on q (heads 0..31) and k (heads 32..39) -----
__global__ void rope_kernel(u16* __restrict__ qkv, const float* __restrict__ cost,
                            const float* __restrict__ sint){
  int i = blockIdx.x*blockDim.x + threadIdx.x;
  int t = i / 2560;
  int r = i % 2560;
  int h = r >> 6, d = r & 63;
  int base = (h < 32) ? h*128 : (4096 + (h-32)*128);
  size_t p1 = (size_t)t*ROWQKV + base + d;
  float x1 = bf2f(qkv[p1]), x2 = bf2f(qkv[p1+64]);
  float c = cost[(t<<6)+d], s = sint[(t<<6)+d];
  qkv[p1]    = f2bf(x1*c - x2*s);
  qkv[p1+64] = f2bf(x2*c + x1*s);
}

// ---------------- flash attention: block = (head, 64-row q tile) ------------
#define KLD 136   // 64 x 128 K tile, padded row
#define VLD 72    // 128 x 64 V^T tile, padded row
#define PLD 72    // 64 x 64 P tile, padded row

__global__ __launch_bounds__(256)
void attn_kernel(const u16* __restrict__ qkv, u16* __restrict__ attn_o)
{
  __shared__ u16 Ks[64*KLD];
  __shared__ u16 Vt[128*VLD];
  __shared__ u16 Ps[64*PLD];
  const int tid = threadIdx.x, lane = tid&63, wid = tid>>6;
  const int l15 = lane&15, l4 = lane>>4;
  const int h  = blockIdx.x & 31;
  const int qt = 31 - (blockIdx.x >> 5);       // heavy tiles first
  const int q0 = qt * 64;
  const int kvh = h >> 2;
  const u16* Qg = qkv + h*128;
  const u16* Kg = qkv + 4096 + kvh*128;
  const u16* Vg = qkv + 5120 + kvh*128;

  bf16x8_t qf[4];
  {
    size_t qrow = (size_t)(q0 + wid*16 + l15);
    #pragma unroll
    for (int kk=0;kk<4;kk++)
      qf[kk] = *(const bf16x8_t*)(Qg + qrow*ROWQKV + kk*32 + l4*8);
  }
  float mrow[4] = {-1e30f,-1e30f,-1e30f,-1e30f};
  float lrow[4] = {0.f,0.f,0.f,0.f};
  f32x4_t oacc[8] = {};
  const float scale = 0.08838834764831845f;  // 1/sqrt(128)

  const int krow = tid >> 2, kd0 = (tid & 3) * 32;
  const int kvp  = tid & 31;          // kv pair (2*kvp, 2*kvp+1)
  const int vd0  = (tid >> 5) * 16;   // d range start

  for (int kt = 0; kt <= qt; ++kt){
    int kv0 = kt * 64;
    {
      const u16* src = Kg + (size_t)(kv0 + krow)*ROWQKV + kd0;
      #pragma unroll
      for (int i=0;i<4;i++)
        *(uint4*)&Ks[krow*KLD + kd0 + i*8] = *(const uint4*)(src + i*8);
      const u16* va = Vg + (size_t)(kv0 + 2*kvp)*ROWQKV + vd0;
      uint4 r0 = *(const uint4*)va,            r1 = *(const uint4*)(va + 8);
      uint4 r2 = *(const uint4*)(va + ROWQKV), r3 = *(const uint4*)(va + ROWQKV + 8);
      const u16* ra = (const u16*)&r0; const u16* rb = (const u16*)&r2;
      #pragma unroll
      for (int e=0;e<8;e++)
        *(uint32_t*)&Vt[(vd0 + e)*VLD + 2*kvp] = (uint32_t)ra[e] | ((uint32_t)rb[e] << 16);
      ra = (const u16*)&r1; rb = (const u16*)&r3;
      #pragma unroll
      for (int e=0;e<8;e++)
        *(uint32_t*)&Vt[(vd0 + 8 + e)*VLD + 2*kvp] = (uint32_t)ra[e] | ((uint32_t)rb[e] << 16);
    }
    __syncthreads();

    f32x4_t sacc[4] = {};
    #pragma unroll
    for (int n=0;n<4;n++){
      #pragma unroll
      for (int kk=0;kk<4;kk++){
        bf16x8_t kf = *(const bf16x8_t*)&Ks[(n*16 + l15)*KLD + kk*32 + l4*8];
        sacc[n] = __builtin_amdgcn_mfma_f32_16x16x32_bf16(qf[kk], kf, sacc[n], 0,0,0);
      }
    }
    float sv[4][4];
    float pmax[4] = {-1e30f,-1e30f,-1e30f,-1e30f};
    bool diag = (kt == qt);
    #pragma unroll
    for (int n=0;n<4;n++){
      int kvcol = kv0 + n*16 + l15;
      #pragma unroll
      for (int j=0;j<4;j++){
        float s = sacc[n][j] * scale;
        int qrow = q0 + wid*16 + l4*4 + j;
        if (diag && kvcol > qrow) s = -1e30f;
        sv[n][j] = s;
        pmax[j] = fmaxf(pmax[j], s);
      }
    }
    #pragma unroll
    for (int off=1; off<16; off<<=1){
      #pragma unroll
      for (int j=0;j<4;j++)
        pmax[j] = fmaxf(pmax[j], __shfl_xor(pmax[j], off, 64));
    }
    float esc[4], rsum[4] = {0.f,0.f,0.f,0.f};
    #pragma unroll
    for (int j=0;j<4;j++){
      float mn = fmaxf(mrow[j], pmax[j]);
      esc[j] = __expf(mrow[j] - mn);
      mrow[j] = mn;
    }
    #pragma unroll
    for (int n=0;n<4;n++){
      #pragma unroll
      for (int j=0;j<4;j++){
        float p = __expf(sv[n][j] - mrow[j]);
        sv[n][j] = p;
        rsum[j] += p;
      }
    }
    #pragma unroll
    for (int off=1; off<16; off<<=1){
      #pragma unroll
      for (int j=0;j<4;j++)
        rsum[j] += __shfl_xor(rsum[j], off, 64);
    }
    #pragma unroll
    for (int j=0;j<4;j++) lrow[j] = lrow[j]*esc[j] + rsum[j];
    #pragma unroll
    for (int n=0;n<8;n++){
      #pragma unroll
      for (int j=0;j<4;j++) oacc[n][j] *= esc[j];
    }
    #pragma unroll
    for (int n=0;n<4;n++){
      #pragma unroll
      for (int j=0;j<4;j++)
        Ps[(wid*16 + l4*4 + j)*PLD + n*16 + l15] = f2bf(sv[n][j]);
    }
    #pragma unroll
    for (int kk=0;kk<2;kk++){
      bf16x8_t pf = *(const bf16x8_t*)&Ps[(wid*16 + l15)*PLD + kk*32 + l4*8];
      #pragma unroll
      for (int n=0;n<8;n++){
        bf16x8_t vf = *(const bf16x8_t*)&Vt[(n*16 + l15)*VLD + kk*32 + l4*8];
        oacc[n] = __builtin_amdgcn_mfma_f32_16x16x32_bf16(pf, vf, oacc[n], 0,0,0);
      }
    }
    __syncthreads();
  }

  #pragma unroll
  for (int n=0;n<8;n++){
    #pragma unroll
    for (int j=0;j<4;j++){
      int qrow = q0 + wid*16 + l4*4 + j;
      int col  = h*128 + n*16 + l15;
      attn_o[(size_t)qrow*HID + col] = f2bf(oacc[n][j] / lrow[j]);
    }
  }
}

// ---------------- launcher ----------------
extern "C" void kernel_launch(void* const* d_in, const int* in_sizes, int n_in,
                              void* d_out, int out_size, void* d_ws, size_t ws_size,
                              hipStream_t stream)
{
  const float* hs = (const float*)d_in[0];
  const int*  pos = (const int*)d_in[1];
  const float* Wq = (const float*)d_in[2];
  const float* bq = (const float*)d_in[3];
  const float* Wk = (const float*)d_in[4];
  const float* bk = (const float*)d_in[5];
  const float* Wv = (const float*)d_in[6];
  const float* bv = (const float*)d_in[7];
  const float* Wo = (const float*)d_in[8];
  const float* bo = (const float*)d_in[9];
  float* out = (float*)d_out;

  char* ws = (char*)d_ws;
  u16* hs_bf   = (u16*)ws;  ws += (size_t)2048*4096*2;
  u16* Wqkv_bf = (u16*)ws;  ws += (size_t)6144*4096*2;
  u16* Wo_bf   = (u16*)ws;  ws += (size_t)4096*4096*2;
  u16* qkv     = (u16*)ws;  ws += (size_t)2048*6144*2;
  u16* attn_b  = (u16*)ws;  ws += (size_t)2048*4096*2;
  float* bqkv  = (float*)ws; ws += (size_t)6144*4;
  float* cost  = (float*)ws; ws += (size_t)2048*64*4;
  float* sint  = (float*)ws; ws += (size_t)2048*64*4;

  {
    int n8 = 2048*4096/8;
    cvt_kernel<<<(n8+255)/256, 256, 0, stream>>>(hs, hs_bf, n8);
    n8 = 4096*4096/8;
    cvt_kernel<<<(n8+255)/256, 256, 0, stream>>>(Wq, Wqkv_bf, n8);
    n8 = 1024*4096/8;
    cvt_kernel<<<(n8+255)/256, 256, 0, stream>>>(Wk, Wqkv_bf + (size_t)4096*4096, n8);
    cvt_kernel<<<(n8+255)/256, 256, 0, stream>>>(Wv, Wqkv_bf + (size_t)5120*4096, n8);
    n8 = 4096*4096/8;
    cvt_kernel<<<(n8+255)/256, 256, 0, stream>>>(Wo, Wo_bf, n8);
  }
  setup_kernel<<<(T_SEQ*64 + 255)/256, 256, 0, stream>>>(bq, bk, bv, pos, bqkv, cost, sint);

  // QKV projection: [2048,6144]
  gemm_8p<true><<<dim3(6144/BN8, 2048/BM8), 512, 0, stream>>>(hs_bf, Wqkv_bf, bqkv, qkv, nullptr, 4096, 6144);
  // RoPE on q,k
  rope_kernel<<<(T_SEQ*40*64)/256, 256, 0, stream>>>(qkv, cost, sint);
  // attention
  attn_kernel<<<1024, 256, 0, stream>>>(qkv, attn_b);
  // output projection: [2048,4096] fp32 + bias
  gemm_8p<false><<<dim3(4096/BN8, 2048/BM8), 512, 0, stream>>>(attn_b, Wo_bf, bo, nullptr, out, 4096, 4096);
}

// Round 8
// 398.303 us; speedup vs baseline: 2.3199x; 1.0114x over previous
//
#include <hip/hip_runtime.h>
#include <stdint.h>

typedef unsigned short u16;
typedef __bf16 bf16x8_t __attribute__((ext_vector_type(8)));
typedef float f32x4_t __attribute__((ext_vector_type(4)));

#define T_SEQ 2048
#define HID 4096
#define ROWQKV 6144

__device__ __forceinline__ float bf2f(u16 x){ return __uint_as_float(((uint32_t)x)<<16); }
__device__ __forceinline__ u16 f2bf(float f){
  uint32_t u = __float_as_uint(f);
  return (u16)((u + 0x7fffu + ((u>>16)&1u)) >> 16);
}

__device__ __forceinline__ void gload16(const void* g, void* l){
  __builtin_amdgcn_global_load_lds(
      (const __attribute__((address_space(1))) uint32_t*)g,
      (__attribute__((address_space(3))) uint32_t*)l, 16, 0, 0);
}

// ---------------- fp32 -> bf16 conversion (8 elems / thread) ----------------
__global__ void cvt_kernel(const float* __restrict__ src, u16* __restrict__ dst, int n8){
  int i = blockIdx.x*blockDim.x + threadIdx.x;
  if (i >= n8) return;
  const float4* s = (const float4*)src;
  float4 a = s[2*i], b = s[2*i+1];
  union { u16 u[8]; uint4 v; } o;
  o.u[0]=f2bf(a.x); o.u[1]=f2bf(a.y); o.u[2]=f2bf(a.z); o.u[3]=f2bf(a.w);
  o.u[4]=f2bf(b.x); o.u[5]=f2bf(b.y); o.u[6]=f2bf(b.z); o.u[7]=f2bf(b.w);
  ((uint4*)dst)[i] = o.v;
}

// ---------------- bias concat + rope tables ----------------
__global__ void setup_kernel(const float* __restrict__ bq, const float* __restrict__ bk,
                             const float* __restrict__ bv, const int* __restrict__ pos,
                             float* __restrict__ bqkv, float* __restrict__ cost,
                             float* __restrict__ sint){
  int i = blockIdx.x*blockDim.x + threadIdx.x;
  if (i < 6144) bqkv[i] = (i<4096) ? bq[i] : ((i<5120) ? bk[i-4096] : bv[i-5120]);
  if (i < T_SEQ*64){
    int t = i >> 6, d = i & 63;
    float inv = powf(10000.0f, -(float)(2*d) / 128.0f);
    float ang = (float)pos[t] * inv;
    cost[i] = cosf(ang);
    sint[i] = sinf(ang);
  }
}

// ------- GEMM 256x256 4-phase (m201 geometry): C = A[M,K]*B[N,K]^T + bias ---
// 512 thr / 8 waves (2M x 4N), wave owns 128x64 C. BK=64.
// LDS: 2 bufs x (A 256x64 + B 256x64) = 2 x 64KB = 128KB, linear + 16B XOR swz.
// Phase p = (m-half, kk): 16 MFMA; B-frags read on kk-change, held across halves.
// Staging: tile t+1's A staged in ph0, B in ph1 (8 gloads, wave-uniform dest);
// vmcnt(0) at tile end waits on loads issued 2-3 phases earlier (drain ~0).
#define BUF2 32768   // elems per buffer (A 16384 + B 16384)

#define GBAR __builtin_amdgcn_s_barrier()
#define LGKM0 do{ asm volatile("s_waitcnt lgkmcnt(0)" ::: "memory"); \
                  __builtin_amdgcn_sched_barrier(0); }while(0)

#define AREAD2(mh, ck) do{ \
  const u16* ab = &lds[cur + aoff + (mh)*4096]; \
  afr[0] = *(const bf16x8_t*)&ab[0*1024 + (ck)]; \
  afr[1] = *(const bf16x8_t*)&ab[1*1024 + (ck)]; \
  afr[2] = *(const bf16x8_t*)&ab[2*1024 + (ck)]; \
  afr[3] = *(const bf16x8_t*)&ab[3*1024 + (ck)]; }while(0)

#define BREAD2(ck) do{ \
  const u16* bb = &lds[cur + boff]; \
  bfr[0] = *(const bf16x8_t*)&bb[0*1024 + (ck)]; \
  bfr[1] = *(const bf16x8_t*)&bb[1*1024 + (ck)]; \
  bfr[2] = *(const bf16x8_t*)&bb[2*1024 + (ck)]; \
  bfr[3] = *(const bf16x8_t*)&bb[3*1024 + (ck)]; }while(0)

#define MM16(mh) do{ \
  _Pragma("unroll") \
  for (int mi=0; mi<4; ++mi){ \
    _Pragma("unroll") \
    for (int n=0; n<4; ++n) \
      acc[(mh)*4+mi][n] = __builtin_amdgcn_mfma_f32_16x16x32_bf16(afr[mi], bfr[n], acc[(mh)*4+mi][n],0,0,0); \
  } }while(0)

template<bool OUT_BF16>
__global__ __launch_bounds__(512, 2)
void gemm_t2(const u16* __restrict__ A, const u16* __restrict__ B,
             const float* __restrict__ bias, u16* __restrict__ Cb,
             float* __restrict__ Cf, int K, int N)
{
  __shared__ u16 lds[2*BUF2];
  const int tid = threadIdx.x, lane = tid & 63, w = tid >> 6;
  const int l15 = lane & 15, l4 = lane >> 4;
  const int wm = w >> 2, wn = w & 3;

  // XCD-aware bijective block swizzle (both grids are multiples of 8)
  const int nwg = gridDim.x * gridDim.y;
  int flat = blockIdx.y * gridDim.x + blockIdx.x;
  flat = (flat & 7) * (nwg >> 3) + (flat >> 3);
  const int bx = flat % gridDim.x, by = flat / gridDim.x;
  const int bm = by * 256, bn = bx * 256;

  // staging geometry: load covers 64 rows; thread -> row w*8+(l>>3), 16B blk l&7
  const int srow = w*8 + (lane >> 3);
  const int swc  = ((lane & 7) ^ (lane >> 3)) * 8;   // pre-swizzled col (both sides)
  const u16* pAlo = A + (size_t)(bm +       srow)*K + swc;
  const u16* pAhi = A + (size_t)(bm + 128 + srow)*K + swc;
  const u16* pBlo = B + (size_t)(bn +       srow)*K + swc;
  const u16* pBhi = B + (size_t)(bn + 128 + srow)*K + swc;
  const size_t j64 = (size_t)64*K;
  const int wu = (w*8)*64;             // wave-uniform LDS elem offset within region

  // fragment-read constants (swizzled 16B block on read side)
  const int cA0 = ((0 + l4) ^ (l15 & 7)) * 8;   // kk=0
  const int cA1 = ((4 + l4) ^ (l15 & 7)) * 8;   // kk=1
  const int aoff = (wm*128 + l15) * 64;          // + mh*4096 + mi*1024
  const int boff = 16384 + (wn*64 + l15) * 64;   // + n*1024

  f32x4_t acc[8][4] = {};
  const int KT = K >> 6;

  // prologue: stage tile 0 into buf 0
  gload16(pAlo,       &lds[0     + wu]);  gload16(pAlo + j64, &lds[4096  + wu]);
  gload16(pAhi,       &lds[8192  + wu]);  gload16(pAhi + j64, &lds[12288 + wu]);
  gload16(pBlo,       &lds[16384 + wu]);  gload16(pBlo + j64, &lds[20480 + wu]);
  gload16(pBhi,       &lds[24576 + wu]);  gload16(pBhi + j64, &lds[28672 + wu]);
  pAlo += 64; pAhi += 64; pBlo += 64; pBhi += 64;
  asm volatile("s_waitcnt vmcnt(0)" ::: "memory");
  GBAR;

  for (int t = 0; t < KT; ++t){
    const int cur = (t & 1) * BUF2;
    const int nxt = ((t + 1) & 1) * BUF2;
    const bool st = (t + 1 < KT);
    bf16x8_t afr[4], bfr[4];

    // ph0: B(kk0) + A(mh0,kk0) | stage A(t+1)
    BREAD2(cA0); AREAD2(0, cA0);
    if (st){
      gload16(pAlo,       &lds[nxt + 0     + wu]);
      gload16(pAlo + j64, &lds[nxt + 4096  + wu]);
      gload16(pAhi,       &lds[nxt + 8192  + wu]);
      gload16(pAhi + j64, &lds[nxt + 12288 + wu]);
    }
    GBAR; LGKM0;
    __builtin_amdgcn_s_setprio(1); MM16(0); __builtin_amdgcn_s_setprio(0);
    GBAR;

    // ph1: A(mh1,kk0), B held | stage B(t+1)
    AREAD2(1, cA0);
    if (st){
      gload16(pBlo,       &lds[nxt + 16384 + wu]);
      gload16(pBlo + j64, &lds[nxt + 20480 + wu]);
      gload16(pBhi,       &lds[nxt + 24576 + wu]);
      gload16(pBhi + j64, &lds[nxt + 28672 + wu]);
      pAlo += 64; pAhi += 64; pBlo += 64; pBhi += 64;
    }
    GBAR; LGKM0;
    __builtin_amdgcn_s_setprio(1); MM16(1); __builtin_amdgcn_s_setprio(0);
    GBAR;

    // ph2: B(kk1) + A(mh0,kk1)
    BREAD2(cA1); AREAD2(0, cA1);
    GBAR; LGKM0;
    __builtin_amdgcn_s_setprio(1); MM16(0); __builtin_amdgcn_s_setprio(0);
    GBAR;

    // ph3: A(mh1,kk1), B held | tile-end drain (loads issued 2-3 phases ago)
    AREAD2(1, cA1);
    GBAR; LGKM0;
    __builtin_amdgcn_s_setprio(1); MM16(1); __builtin_amdgcn_s_setprio(0);
    if (st) asm volatile("s_waitcnt vmcnt(0)" ::: "memory");
    GBAR;
  }

  #pragma unroll
  for (int m=0;m<8;m++){
    #pragma unroll
    for (int n=0;n<4;n++){
      #pragma unroll
      for (int j=0;j<4;j++){
        int row = bm + wm*128 + (m>>2)*64 + (m&3)*16 + l4*4 + j;
        int col = bn + wn*64 + n*16 + l15;
        float v = acc[m][n][j] + bias[col];
        if constexpr (OUT_BF16) Cb[(size_t)row*N + col] = f2bf(v);
        else                    Cf[(size_t)row*N + col] = v;
      }
    }
  }
}

// ---------------- RoPE in-place on q (heads 0..31) and k (heads 32..39) -----
__global__ void rope_kernel(u16* __restrict__ qkv, const float* __restrict__ cost,
                            const float* __restrict__ sint){
  int i = blockIdx.x*blockDim.x + threadIdx.x;
  int t = i / 2560;
  int r = i % 2560;
  int h = r >> 6, d = r & 63;
  int base = (h < 32) ? h*128 : (4096 + (h-32)*128);
  size_t p1 = (size_t)t*ROWQKV + base + d;
  float x1 = bf2f(qkv[p1]), x2 = bf2f(qkv[p1+64]);
  float c = cost[(t<<6)+d], s = sint[(t<<6)+d];
  qkv[p1]    = f2bf(x1*c - x2*s);
  qkv[p1+64] = f2bf(x2*c + x1*s);
}

// ---------------- flash attention: block = (head, 64-row q tile) ------------
#define KLD 136   // 64 x 128 K tile, padded row
#define VLD 72    // 128 x 64 V^T tile, padded row
#define PLD 72    // 64 x 64 P tile, padded row

__global__ __launch_bounds__(256)
void attn_kernel(const u16* __restrict__ qkv, u16* __restrict__ attn_o)
{
  __shared__ u16 Ks[64*KLD];
  __shared__ u16 Vt[128*VLD];
  __shared__ u16 Ps[64*PLD];
  const int tid = threadIdx.x, lane = tid&63, wid = tid>>6;
  const int l15 = lane&15, l4 = lane>>4;
  const int h  = blockIdx.x & 31;
  const int qt = 31 - (blockIdx.x >> 5);       // heavy tiles first
  const int q0 = qt * 64;
  const int kvh = h >> 2;
  const u16* Qg = qkv + h*128;
  const u16* Kg = qkv + 4096 + kvh*128;
  const u16* Vg = qkv + 5120 + kvh*128;

  bf16x8_t qf[4];
  {
    size_t qrow = (size_t)(q0 + wid*16 + l15);
    #pragma unroll
    for (int kk=0;kk<4;kk++)
      qf[kk] = *(const bf16x8_t*)(Qg + qrow*ROWQKV + kk*32 + l4*8);
  }
  float mrow[4] = {-1e30f,-1e30f,-1e30f,-1e30f};
  float lrow[4] = {0.f,0.f,0.f,0.f};
  f32x4_t oacc[8] = {};
  const float scale = 0.08838834764831845f;  // 1/sqrt(128)

  const int krow = tid >> 2, kd0 = (tid & 3) * 32;
  const int kvp  = tid & 31;          // kv pair (2*kvp, 2*kvp+1)
  const int vd0  = (tid >> 5) * 16;   // d range start

  for (int kt = 0; kt <= qt; ++kt){
    int kv0 = kt * 64;
    {
      const u16* src = Kg + (size_t)(kv0 + krow)*ROWQKV + kd0;
      #pragma unroll
      for (int i=0;i<4;i++)
        *(uint4*)&Ks[krow*KLD + kd0 + i*8] = *(const uint4*)(src + i*8);
      const u16* va = Vg + (size_t)(kv0 + 2*kvp)*ROWQKV + vd0;
      uint4 r0 = *(const uint4*)va,            r1 = *(const uint4*)(va + 8);
      uint4 r2 = *(const uint4*)(va + ROWQKV), r3 = *(const uint4*)(va + ROWQKV + 8);
      const u16* ra = (const u16*)&r0; const u16* rb = (const u16*)&r2;
      #pragma unroll
      for (int e=0;e<8;e++)
        *(uint32_t*)&Vt[(vd0 + e)*VLD + 2*kvp] = (uint32_t)ra[e] | ((uint32_t)rb[e] << 16);
      ra = (const u16*)&r1; rb = (const u16*)&r3;
      #pragma unroll
      for (int e=0;e<8;e++)
        *(uint32_t*)&Vt[(vd0 + 8 + e)*VLD + 2*kvp] = (uint32_t)ra[e] | ((uint32_t)rb[e] << 16);
    }
    __syncthreads();

    f32x4_t sacc[4] = {};
    #pragma unroll
    for (int n=0;n<4;n++){
      #pragma unroll
      for (int kk=0;kk<4;kk++){
        bf16x8_t kf = *(const bf16x8_t*)&Ks[(n*16 + l15)*KLD + kk*32 + l4*8];
        sacc[n] = __builtin_amdgcn_mfma_f32_16x16x32_bf16(qf[kk], kf, sacc[n], 0,0,0);
      }
    }
    float sv[4][4];
    float pmax[4] = {-1e30f,-1e30f,-1e30f,-1e30f};
    bool diag = (kt == qt);
    #pragma unroll
    for (int n=0;n<4;n++){
      int kvcol = kv0 + n*16 + l15;
      #pragma unroll
      for (int j=0;j<4;j++){
        float s = sacc[n][j] * scale;
        int qrow = q0 + wid*16 + l4*4 + j;
        if (diag && kvcol > qrow) s = -1e30f;
        sv[n][j] = s;
        pmax[j] = fmaxf(pmax[j], s);
      }
    }
    #pragma unroll
    for (int off=1; off<16; off<<=1){
      #pragma unroll
      for (int j=0;j<4;j++)
        pmax[j] = fmaxf(pmax[j], __shfl_xor(pmax[j], off, 64));
    }
    float esc[4], rsum[4] = {0.f,0.f,0.f,0.f};
    #pragma unroll
    for (int j=0;j<4;j++){
      float mn = fmaxf(mrow[j], pmax[j]);
      esc[j] = __expf(mrow[j] - mn);
      mrow[j] = mn;
    }
    #pragma unroll
    for (int n=0;n<4;n++){
      #pragma unroll
      for (int j=0;j<4;j++){
        float p = __expf(sv[n][j] - mrow[j]);
        sv[n][j] = p;
        rsum[j] += p;
      }
    }
    #pragma unroll
    for (int off=1; off<16; off<<=1){
      #pragma unroll
      for (int j=0;j<4;j++)
        rsum[j] += __shfl_xor(rsum[j], off, 64);
    }
    #pragma unroll
    for (int j=0;j<4;j++) lrow[j] = lrow[j]*esc[j] + rsum[j];
    #pragma unroll
    for (int n=0;n<8;n++){
      #pragma unroll
      for (int j=0;j<4;j++) oacc[n][j] *= esc[j];
    }
    #pragma unroll
    for (int n=0;n<4;n++){
      #pragma unroll
      for (int j=0;j<4;j++)
        Ps[(wid*16 + l4*4 + j)*PLD + n*16 + l15] = f2bf(sv[n][j]);
    }
    #pragma unroll
    for (int kk=0;kk<2;kk++){
      bf16x8_t pf = *(const bf16x8_t*)&Ps[(wid*16 + l15)*PLD + kk*32 + l4*8];
      #pragma unroll
      for (int n=0;n<8;n++){
        bf16x8_t vf = *(const bf16x8_t*)&Vt[(n*16 + l15)*VLD + kk*32 + l4*8];
        oacc[n] = __builtin_amdgcn_mfma_f32_16x16x32_bf16(pf, vf, oacc[n], 0,0,0);
      }
    }
    __syncthreads();
  }

  #pragma unroll
  for (int n=0;n<8;n++){
    #pragma unroll
    for (int j=0;j<4;j++){
      int qrow = q0 + wid*16 + l4*4 + j;
      int col  = h*128 + n*16 + l15;
      attn_o[(size_t)qrow*HID + col] = f2bf(oacc[n][j] / lrow[j]);
    }
  }
}

// ---------------- launcher ----------------
extern "C" void kernel_launch(void* const* d_in, const int* in_sizes, int n_in,
                              void* d_out, int out_size, void* d_ws, size_t ws_size,
                              hipStream_t stream)
{
  const float* hs = (const float*)d_in[0];
  const int*  pos = (const int*)d_in[1];
  const float* Wq = (const float*)d_in[2];
  const float* bq = (const float*)d_in[3];
  const float* Wk = (const float*)d_in[4];
  const float* bk = (const float*)d_in[5];
  const float* Wv = (const float*)d_in[6];
  const float* bv = (const float*)d_in[7];
  const float* Wo = (const float*)d_in[8];
  const float* bo = (const float*)d_in[9];
  float* out = (float*)d_out;

  char* ws = (char*)d_ws;
  u16* hs_bf   = (u16*)ws;  ws += (size_t)2048*4096*2;
  u16* Wqkv_bf = (u16*)ws;  ws += (size_t)6144*4096*2;
  u16* Wo_bf   = (u16*)ws;  ws += (size_t)4096*4096*2;
  u16* qkv     = (u16*)ws;  ws += (size_t)2048*6144*2;
  u16* attn_b  = (u16*)ws;  ws += (size_t)2048*4096*2;
  float* bqkv  = (float*)ws; ws += (size_t)6144*4;
  float* cost  = (float*)ws; ws += (size_t)2048*64*4;
  float* sint  = (float*)ws; ws += (size_t)2048*64*4;

  {
    int n8 = 2048*4096/8;
    cvt_kernel<<<(n8+255)/256, 256, 0, stream>>>(hs, hs_bf, n8);
    n8 = 4096*4096/8;
    cvt_kernel<<<(n8+255)/256, 256, 0, stream>>>(Wq, Wqkv_bf, n8);
    n8 = 1024*4096/8;
    cvt_kernel<<<(n8+255)/256, 256, 0, stream>>>(Wk, Wqkv_bf + (size_t)4096*4096, n8);
    cvt_kernel<<<(n8+255)/256, 256, 0, stream>>>(Wv, Wqkv_bf + (size_t)5120*4096, n8);
    n8 = 4096*4096/8;
    cvt_kernel<<<(n8+255)/256, 256, 0, stream>>>(Wo, Wo_bf, n8);
  }
  setup_kernel<<<(T_SEQ*64 + 255)/256, 256, 0, stream>>>(bq, bk, bv, pos, bqkv, cost, sint);

  // QKV projection: [2048,6144] — grid 24x8 = 192 blocks
  gemm_t2<true><<<dim3(6144/256, 2048/256), 512, 0, stream>>>(hs_bf, Wqkv_bf, bqkv, qkv, nullptr, 4096, 6144);
  // RoPE on q,k
  rope_kernel<<<(T_SEQ*40*64)/256, 256, 0, stream>>>(qkv, cost, sint);
  // attention
  attn_kernel<<<1024, 256, 0, stream>>>(qkv, attn_b);
  // output projection: [2048,4096] fp32 + bias — grid 16x8 = 128 blocks
  gemm_t2<false><<<dim3(4096/256, 2048/256), 512, 0, stream>>>(attn_b, Wo_bf, bo, nullptr, out, 4096, 4096);
}

// Round 9
// 394.317 us; speedup vs baseline: 2.3434x; 1.0101x over previous
//
#include <hip/hip_runtime.h>
#include <stdint.h>

typedef unsigned short u16;
typedef __bf16 bf16x8_t __attribute__((ext_vector_type(8)));
typedef float f32x4_t __attribute__((ext_vector_type(4)));

#define T_SEQ 2048
#define HID 4096
#define ROWQKV 6144

__device__ __forceinline__ float bf2f(u16 x){ return __uint_as_float(((uint32_t)x)<<16); }
__device__ __forceinline__ u16 f2bf(float f){
  uint32_t u = __float_as_uint(f);
  return (u16)((u + 0x7fffu + ((u>>16)&1u)) >> 16);
}

__device__ __forceinline__ void gload16(const void* g, void* l){
  __builtin_amdgcn_global_load_lds(
      (const __attribute__((address_space(1))) uint32_t*)g,
      (__attribute__((address_space(3))) uint32_t*)l, 16, 0, 0);
}

// ---------------- fp32 -> bf16 conversion (8 elems / thread) ----------------
__global__ void cvt_kernel(const float* __restrict__ src, u16* __restrict__ dst, int n8){
  int i = blockIdx.x*blockDim.x + threadIdx.x;
  if (i >= n8) return;
  const float4* s = (const float4*)src;
  float4 a = s[2*i], b = s[2*i+1];
  union { u16 u[8]; uint4 v; } o;
  o.u[0]=f2bf(a.x); o.u[1]=f2bf(a.y); o.u[2]=f2bf(a.z); o.u[3]=f2bf(a.w);
  o.u[4]=f2bf(b.x); o.u[5]=f2bf(b.y); o.u[6]=f2bf(b.z); o.u[7]=f2bf(b.w);
  ((uint4*)dst)[i] = o.v;
}

// ---------------- bias concat + rope tables ----------------
__global__ void setup_kernel(const float* __restrict__ bq, const float* __restrict__ bk,
                             const float* __restrict__ bv, const int* __restrict__ pos,
                             float* __restrict__ bqkv, float* __restrict__ cost,
                             float* __restrict__ sint){
  int i = blockIdx.x*blockDim.x + threadIdx.x;
  if (i < 6144) bqkv[i] = (i<4096) ? bq[i] : ((i<5120) ? bk[i-4096] : bv[i-5120]);
  if (i < T_SEQ*64){
    int t = i >> 6, d = i & 63;
    float inv = powf(10000.0f, -(float)(2*d) / 128.0f);
    float ang = (float)pos[t] * inv;
    cost[i] = cosf(ang);
    sint[i] = sinf(ang);
  }
}

// ------- GEMM 256x256 4-phase (m201 geometry): C = A[M,K]*B[N,K]^T + bias ---
#define BUF2 32768   // elems per buffer (A 16384 + B 16384)

#define GBAR __builtin_amdgcn_s_barrier()
#define LGKM0 do{ asm volatile("s_waitcnt lgkmcnt(0)" ::: "memory"); \
                  __builtin_amdgcn_sched_barrier(0); }while(0)

#define AREAD2(mh, ck) do{ \
  const u16* ab = &lds[cur + aoff + (mh)*4096]; \
  afr[0] = *(const bf16x8_t*)&ab[0*1024 + (ck)]; \
  afr[1] = *(const bf16x8_t*)&ab[1*1024 + (ck)]; \
  afr[2] = *(const bf16x8_t*)&ab[2*1024 + (ck)]; \
  afr[3] = *(const bf16x8_t*)&ab[3*1024 + (ck)]; }while(0)

#define BREAD2(ck) do{ \
  const u16* bb = &lds[cur + boff]; \
  bfr[0] = *(const bf16x8_t*)&bb[0*1024 + (ck)]; \
  bfr[1] = *(const bf16x8_t*)&bb[1*1024 + (ck)]; \
  bfr[2] = *(const bf16x8_t*)&bb[2*1024 + (ck)]; \
  bfr[3] = *(const bf16x8_t*)&bb[3*1024 + (ck)]; }while(0)

#define MM16(mh) do{ \
  _Pragma("unroll") \
  for (int mi=0; mi<4; ++mi){ \
    _Pragma("unroll") \
    for (int n=0; n<4; ++n) \
      acc[(mh)*4+mi][n] = __builtin_amdgcn_mfma_f32_16x16x32_bf16(afr[mi], bfr[n], acc[(mh)*4+mi][n],0,0,0); \
  } }while(0)

template<bool OUT_BF16>
__global__ __launch_bounds__(512, 2)
void gemm_t2(const u16* __restrict__ A, const u16* __restrict__ B,
             const float* __restrict__ bias, u16* __restrict__ Cb,
             float* __restrict__ Cf, int K, int N)
{
  __shared__ u16 lds[2*BUF2];
  const int tid = threadIdx.x, lane = tid & 63, w = tid >> 6;
  const int l15 = lane & 15, l4 = lane >> 4;
  const int wm = w >> 2, wn = w & 3;

  const int nwg = gridDim.x * gridDim.y;
  int flat = blockIdx.y * gridDim.x + blockIdx.x;
  flat = (flat & 7) * (nwg >> 3) + (flat >> 3);
  const int bx = flat % gridDim.x, by = flat / gridDim.x;
  const int bm = by * 256, bn = bx * 256;

  const int srow = w*8 + (lane >> 3);
  const int swc  = ((lane & 7) ^ (lane >> 3)) * 8;
  const u16* pAlo = A + (size_t)(bm +       srow)*K + swc;
  const u16* pAhi = A + (size_t)(bm + 128 + srow)*K + swc;
  const u16* pBlo = B + (size_t)(bn +       srow)*K + swc;
  const u16* pBhi = B + (size_t)(bn + 128 + srow)*K + swc;
  const size_t j64 = (size_t)64*K;
  const int wu = (w*8)*64;

  const int cA0 = ((0 + l4) ^ (l15 & 7)) * 8;
  const int cA1 = ((4 + l4) ^ (l15 & 7)) * 8;
  const int aoff = (wm*128 + l15) * 64;
  const int boff = 16384 + (wn*64 + l15) * 64;

  f32x4_t acc[8][4] = {};
  const int KT = K >> 6;

  gload16(pAlo,       &lds[0     + wu]);  gload16(pAlo + j64, &lds[4096  + wu]);
  gload16(pAhi,       &lds[8192  + wu]);  gload16(pAhi + j64, &lds[12288 + wu]);
  gload16(pBlo,       &lds[16384 + wu]);  gload16(pBlo + j64, &lds[20480 + wu]);
  gload16(pBhi,       &lds[24576 + wu]);  gload16(pBhi + j64, &lds[28672 + wu]);
  pAlo += 64; pAhi += 64; pBlo += 64; pBhi += 64;
  asm volatile("s_waitcnt vmcnt(0)" ::: "memory");
  GBAR;

  for (int t = 0; t < KT; ++t){
    const int cur = (t & 1) * BUF2;
    const int nxt = ((t + 1) & 1) * BUF2;
    const bool st = (t + 1 < KT);
    bf16x8_t afr[4], bfr[4];

    BREAD2(cA0); AREAD2(0, cA0);
    if (st){
      gload16(pAlo,       &lds[nxt + 0     + wu]);
      gload16(pAlo + j64, &lds[nxt + 4096  + wu]);
      gload16(pAhi,       &lds[nxt + 8192  + wu]);
      gload16(pAhi + j64, &lds[nxt + 12288 + wu]);
    }
    GBAR; LGKM0;
    __builtin_amdgcn_s_setprio(1); MM16(0); __builtin_amdgcn_s_setprio(0);
    GBAR;

    AREAD2(1, cA0);
    if (st){
      gload16(pBlo,       &lds[nxt + 16384 + wu]);
      gload16(pBlo + j64, &lds[nxt + 20480 + wu]);
      gload16(pBhi,       &lds[nxt + 24576 + wu]);
      gload16(pBhi + j64, &lds[nxt + 28672 + wu]);
      pAlo += 64; pAhi += 64; pBlo += 64; pBhi += 64;
    }
    GBAR; LGKM0;
    __builtin_amdgcn_s_setprio(1); MM16(1); __builtin_amdgcn_s_setprio(0);
    GBAR;

    BREAD2(cA1); AREAD2(0, cA1);
    GBAR; LGKM0;
    __builtin_amdgcn_s_setprio(1); MM16(0); __builtin_amdgcn_s_setprio(0);
    GBAR;

    AREAD2(1, cA1);
    GBAR; LGKM0;
    __builtin_amdgcn_s_setprio(1); MM16(1); __builtin_amdgcn_s_setprio(0);
    if (st) asm volatile("s_waitcnt vmcnt(0)" ::: "memory");
    GBAR;
  }

  #pragma unroll
  for (int m=0;m<8;m++){
    #pragma unroll
    for (int n=0;n<4;n++){
      #pragma unroll
      for (int j=0;j<4;j++){
        int row = bm + wm*128 + (m>>2)*64 + (m&3)*16 + l4*4 + j;
        int col = bn + wn*64 + n*16 + l15;
        float v = acc[m][n][j] + bias[col];
        if constexpr (OUT_BF16) Cb[(size_t)row*N + col] = f2bf(v);
        else                    Cf[(size_t)row*N + col] = v;
      }
    }
  }
}

// ---------------- RoPE in-place on q (heads 0..31) and k (heads 32..39) -----
__global__ void rope_kernel(u16* __restrict__ qkv, const float* __restrict__ cost,
                            const float* __restrict__ sint){
  int i = blockIdx.x*blockDim.x + threadIdx.x;
  int t = i / 2560;
  int r = i % 2560;
  int h = r >> 6, d = r & 63;
  int base = (h < 32) ? h*128 : (4096 + (h-32)*128);
  size_t p1 = (size_t)t*ROWQKV + base + d;
  float x1 = bf2f(qkv[p1]), x2 = bf2f(qkv[p1+64]);
  float c = cost[(t<<6)+d], s = sint[(t<<6)+d];
  qkv[p1]    = f2bf(x1*c - x2*s);
  qkv[p1+64] = f2bf(x2*c + x1*s);
}

// ---------------- flash attention: block = (head, 64-row q tile) ------------
// LDS (elems): K dbuf 2 x [2 half][64 row][64 col] at 0/8192 (gload16, both-
// sides 16B XOR swizzle); Vt [128 d][64 kv] at 16384; Ps [64][64] at 24576.
// All rows stride 64; block16 ^= row&7 (r7-verified zero-conflict pattern).
#define VOFF 16384
#define POFF 24576

__global__ __launch_bounds__(256)
void attn_kernel(const u16* __restrict__ qkv, u16* __restrict__ attn_o)
{
  __shared__ u16 lds[28672];   // 56 KB
  const int tid = threadIdx.x, lane = tid&63, wid = tid>>6;
  const int l15 = lane&15, l4 = lane>>4;
  const int l7 = l15 & 7;
  const int h  = blockIdx.x & 31;
  const int qt = 31 - (blockIdx.x >> 5);       // heavy tiles first
  const int q0 = qt * 64;
  const int kvh = h >> 2;
  const u16* Qg = qkv + h*128;
  const u16* Kg = qkv + 4096 + kvh*128;
  const u16* Vg = qkv + 5120 + kvh*128;

  bf16x8_t qf[4];
  {
    size_t qrow = (size_t)(q0 + wid*16 + l15);
    #pragma unroll
    for (int kk=0;kk<4;kk++)
      qf[kk] = *(const bf16x8_t*)(Qg + qrow*ROWQKV + kk*32 + l4*8);
  }
  float mrow[4] = {-1e30f,-1e30f,-1e30f,-1e30f};
  float lrow[4] = {0.f,0.f,0.f,0.f};
  f32x4_t oacc[8] = {};
  const float scale = 0.08838834764831845f;  // 1/sqrt(128)

  // K staging: wave wid stages chunks c = wid*4+i (1KB each). Lane l covers
  // row (c&7)*8 + (l>>3), 16B block l&7; source pre-swizzled: global block
  // (l&7)^(l>>3), col-half c>>3. Dest linear (rule 21).
  const u16* ksrc[4];
  int kls[4];
  #pragma unroll
  for (int i=0;i<4;i++){
    const int c = wid*4 + i;
    ksrc[i] = Kg + (size_t)((c&7)*8 + (lane>>3))*ROWQKV
               + (c>>3)*64 + ((lane&7)^(lane>>3))*8;
    kls[i] = c*512;
  }
  // V transpose staging: thread owns kv pair (2*kvp,+1) x d range vd0..+15
  const int kvp = tid & 31;
  const int vd0 = (tid >> 5) * 16;
  uint4 rv[4];

  // prologue: K(0) -> buf0, V(0) -> regs -> Vt
  #pragma unroll
  for (int i=0;i<4;i++) gload16(ksrc[i], &lds[kls[i]]);
  #pragma unroll
  for (int i=0;i<4;i++) ksrc[i] += (size_t)64*ROWQKV;
  {
    const u16* va = Vg + (size_t)(2*kvp)*ROWQKV + vd0;
    rv[0] = *(const uint4*)va;            rv[1] = *(const uint4*)(va + 8);
    rv[2] = *(const uint4*)(va + ROWQKV); rv[3] = *(const uint4*)(va + ROWQKV + 8);
  }
  __syncthreads();   // drains gloads (vmcnt) + barrier
  {
    const u16* ra = (const u16*)&rv[0]; const u16* rb = (const u16*)&rv[2];
    #pragma unroll
    for (int e=0;e<8;e++)
      *(uint32_t*)&lds[VOFF + (vd0+e)*64 + ((kvp>>2)^(e&7))*8 + 2*(kvp&3)]
          = (uint32_t)ra[e] | ((uint32_t)rb[e] << 16);
    ra = (const u16*)&rv[1]; rb = (const u16*)&rv[3];
    #pragma unroll
    for (int e=0;e<8;e++)
      *(uint32_t*)&lds[VOFF + (vd0+8+e)*64 + ((kvp>>2)^(e&7))*8 + 2*(kvp&3)]
          = (uint32_t)ra[e] | ((uint32_t)rb[e] << 16);
  }
  __syncthreads();

  for (int kt = 0; kt <= qt; ++kt){
    const int kv0 = kt * 64;
    const int kcur = (kt & 1) * 8192;
    const bool pre = (kt < qt);
    if (pre){
      const int knxt = ((kt+1) & 1) * 8192;
      #pragma unroll
      for (int i=0;i<4;i++) gload16(ksrc[i], &lds[knxt + kls[i]]);
      #pragma unroll
      for (int i=0;i<4;i++) ksrc[i] += (size_t)64*ROWQKV;
      const u16* va = Vg + (size_t)(kv0 + 64 + 2*kvp)*ROWQKV + vd0;
      rv[0] = *(const uint4*)va;            rv[1] = *(const uint4*)(va + 8);
      rv[2] = *(const uint4*)(va + ROWQKV); rv[3] = *(const uint4*)(va + ROWQKV + 8);
    }

    // S = Q K^T  (wave: 16 q rows x 64 kv)
    f32x4_t sacc[4] = {};
    #pragma unroll
    for (int n=0;n<4;n++){
      #pragma unroll
      for (int kk=0;kk<4;kk++){
        bf16x8_t kf = *(const bf16x8_t*)&lds[kcur + (kk>>1)*4096
                        + (n*16+l15)*64 + (((kk&1)*4 + l4) ^ l7)*8];
        sacc[n] = __builtin_amdgcn_mfma_f32_16x16x32_bf16(qf[kk], kf, sacc[n], 0,0,0);
      }
    }
    float sv[4][4];
    float pmax[4] = {-1e30f,-1e30f,-1e30f,-1e30f};
    bool diag = (kt == qt);
    #pragma unroll
    for (int n=0;n<4;n++){
      int kvcol = kv0 + n*16 + l15;
      #pragma unroll
      for (int j=0;j<4;j++){
        float s = sacc[n][j] * scale;
        int qrow = q0 + wid*16 + l4*4 + j;
        if (diag && kvcol > qrow) s = -1e30f;
        sv[n][j] = s;
        pmax[j] = fmaxf(pmax[j], s);
      }
    }
    #pragma unroll
    for (int off=1; off<16; off<<=1){
      #pragma unroll
      for (int j=0;j<4;j++)
        pmax[j] = fmaxf(pmax[j], __shfl_xor(pmax[j], off, 64));
    }
    float esc[4], rsum[4] = {0.f,0.f,0.f,0.f};
    #pragma unroll
    for (int j=0;j<4;j++){
      float mn = fmaxf(mrow[j], pmax[j]);
      esc[j] = __expf(mrow[j] - mn);
      mrow[j] = mn;
    }
    #pragma unroll
    for (int n=0;n<4;n++){
      #pragma unroll
      for (int j=0;j<4;j++){
        float p = __expf(sv[n][j] - mrow[j]);
        sv[n][j] = p;
        rsum[j] += p;
      }
    }
    #pragma unroll
    for (int off=1; off<16; off<<=1){
      #pragma unroll
      for (int j=0;j<4;j++)
        rsum[j] += __shfl_xor(rsum[j], off, 64);
    }
    #pragma unroll
    for (int j=0;j<4;j++) lrow[j] = lrow[j]*esc[j] + rsum[j];
    #pragma unroll
    for (int n=0;n<8;n++){
      #pragma unroll
      for (int j=0;j<4;j++) oacc[n][j] *= esc[j];
    }
    // P -> LDS (wave-private strip, swizzled)
    #pragma unroll
    for (int n=0;n<4;n++){
      #pragma unroll
      for (int j=0;j<4;j++)
        lds[POFF + (wid*16 + l4*4 + j)*64
            + (((n*2 + (l15>>3)) ^ ((l4*4+j)&7))*8) + l7] = f2bf(sv[n][j]);
    }
    // O += P V   (A = P strip row l15, B = Vt)
    #pragma unroll
    for (int kk=0;kk<2;kk++){
      const int blk = ((kk*4 + l4) ^ l7)*8;
      bf16x8_t pf = *(const bf16x8_t*)&lds[POFF + (wid*16 + l15)*64 + blk];
      #pragma unroll
      for (int n=0;n<8;n++){
        bf16x8_t vf = *(const bf16x8_t*)&lds[VOFF + (n*16 + l15)*64 + blk];
        oacc[n] = __builtin_amdgcn_mfma_f32_16x16x32_bf16(pf, vf, oacc[n], 0,0,0);
      }
    }
    __syncthreads();   // PV done all waves; drains next-tile gloads/V loads
    if (pre){
      const u16* ra = (const u16*)&rv[0]; const u16* rb = (const u16*)&rv[2];
      #pragma unroll
      for (int e=0;e<8;e++)
        *(uint32_t*)&lds[VOFF + (vd0+e)*64 + ((kvp>>2)^(e&7))*8 + 2*(kvp&3)]
            = (uint32_t)ra[e] | ((uint32_t)rb[e] << 16);
      ra = (const u16*)&rv[1]; rb = (const u16*)&rv[3];
      #pragma unroll
      for (int e=0;e<8;e++)
        *(uint32_t*)&lds[VOFF + (vd0+8+e)*64 + ((kvp>>2)^(e&7))*8 + 2*(kvp&3)]
            = (uint32_t)ra[e] | ((uint32_t)rb[e] << 16);
    }
    __syncthreads();
  }

  #pragma unroll
  for (int n=0;n<8;n++){
    #pragma unroll
    for (int j=0;j<4;j++){
      int qrow = q0 + wid*16 + l4*4 + j;
      int col  = h*128 + n*16 + l15;
      attn_o[(size_t)qrow*HID + col] = f2bf(oacc[n][j] / lrow[j]);
    }
  }
}

// ---------------- launcher ----------------
extern "C" void kernel_launch(void* const* d_in, const int* in_sizes, int n_in,
                              void* d_out, int out_size, void* d_ws, size_t ws_size,
                              hipStream_t stream)
{
  const float* hs = (const float*)d_in[0];
  const int*  pos = (const int*)d_in[1];
  const float* Wq = (const float*)d_in[2];
  const float* bq = (const float*)d_in[3];
  const float* Wk = (const float*)d_in[4];
  const float* bk = (const float*)d_in[5];
  const float* Wv = (const float*)d_in[6];
  const float* bv = (const float*)d_in[7];
  const float* Wo = (const float*)d_in[8];
  const float* bo = (const float*)d_in[9];
  float* out = (float*)d_out;

  char* ws = (char*)d_ws;
  u16* hs_bf   = (u16*)ws;  ws += (size_t)2048*4096*2;
  u16* Wqkv_bf = (u16*)ws;  ws += (size_t)6144*4096*2;
  u16* Wo_bf   = (u16*)ws;  ws += (size_t)4096*4096*2;
  u16* qkv     = (u16*)ws;  ws += (size_t)2048*6144*2;
  u16* attn_b  = (u16*)ws;  ws += (size_t)2048*4096*2;
  float* bqkv  = (float*)ws; ws += (size_t)6144*4;
  float* cost  = (float*)ws; ws += (size_t)2048*64*4;
  float* sint  = (float*)ws; ws += (size_t)2048*64*4;

  {
    int n8 = 2048*4096/8;
    cvt_kernel<<<(n8+255)/256, 256, 0, stream>>>(hs, hs_bf, n8);
    n8 = 4096*4096/8;
    cvt_kernel<<<(n8+255)/256, 256, 0, stream>>>(Wq, Wqkv_bf, n8);
    n8 = 1024*4096/8;
    cvt_kernel<<<(n8+255)/256, 256, 0, stream>>>(Wk, Wqkv_bf + (size_t)4096*4096, n8);
    cvt_kernel<<<(n8+255)/256, 256, 0, stream>>>(Wv, Wqkv_bf + (size_t)5120*4096, n8);
    n8 = 4096*4096/8;
    cvt_kernel<<<(n8+255)/256, 256, 0, stream>>>(Wo, Wo_bf, n8);
  }
  setup_kernel<<<(T_SEQ*64 + 255)/256, 256, 0, stream>>>(bq, bk, bv, pos, bqkv, cost, sint);

  // QKV projection: [2048,6144] — grid 24x8 = 192 blocks
  gemm_t2<true><<<dim3(6144/256, 2048/256), 512, 0, stream>>>(hs_bf, Wqkv_bf, bqkv, qkv, nullptr, 4096, 6144);
  // RoPE on q,k
  rope_kernel<<<(T_SEQ*40*64)/256, 256, 0, stream>>>(qkv, cost, sint);
  // attention
  attn_kernel<<<1024, 256, 0, stream>>>(qkv, attn_b);
  // output projection: [2048,4096] fp32 + bias — grid 16x8 = 128 blocks
  gemm_t2<false><<<dim3(4096/256, 2048/256), 512, 0, stream>>>(attn_b, Wo_bf, bo, nullptr, out, 4096, 4096);
}

// Round 10
// 357.121 us; speedup vs baseline: 2.5875x; 1.1042x over previous
//
#include <hip/hip_runtime.h>
#include <stdint.h>

typedef unsigned short u16;
typedef __bf16 bf16x8_t __attribute__((ext_vector_type(8)));
typedef float f32x4_t __attribute__((ext_vector_type(4)));

#define T_SEQ 2048
#define HID 4096
#define ROWQKV 6144

__device__ __forceinline__ float bf2f(u16 x){ return __uint_as_float(((uint32_t)x)<<16); }
__device__ __forceinline__ u16 f2bf(float f){
  uint32_t u = __float_as_uint(f);
  return (u16)((u + 0x7fffu + ((u>>16)&1u)) >> 16);
}

__device__ __forceinline__ void gload16(const void* g, void* l){
  __builtin_amdgcn_global_load_lds(
      (const __attribute__((address_space(1))) uint32_t*)g,
      (__attribute__((address_space(3))) uint32_t*)l, 16, 0, 0);
}

// ---------------- fp32 -> bf16 conversion (8 elems / thread) ----------------
__global__ void cvt_kernel(const float* __restrict__ src, u16* __restrict__ dst, int n8){
  int i = blockIdx.x*blockDim.x + threadIdx.x;
  if (i >= n8) return;
  const float4* s = (const float4*)src;
  float4 a = s[2*i], b = s[2*i+1];
  union { u16 u[8]; uint4 v; } o;
  o.u[0]=f2bf(a.x); o.u[1]=f2bf(a.y); o.u[2]=f2bf(a.z); o.u[3]=f2bf(a.w);
  o.u[4]=f2bf(b.x); o.u[5]=f2bf(b.y); o.u[6]=f2bf(b.z); o.u[7]=f2bf(b.w);
  ((uint4*)dst)[i] = o.v;
}

// ---------------- bias concat + rope tables ----------------
__global__ void setup_kernel(const float* __restrict__ bq, const float* __restrict__ bk,
                             const float* __restrict__ bv, const int* __restrict__ pos,
                             float* __restrict__ bqkv, float* __restrict__ cost,
                             float* __restrict__ sint){
  int i = blockIdx.x*blockDim.x + threadIdx.x;
  if (i < 6144) bqkv[i] = (i<4096) ? bq[i] : ((i<5120) ? bk[i-4096] : bv[i-5120]);
  if (i < T_SEQ*64){
    int t = i >> 6, d = i & 63;
    float inv = powf(10000.0f, -(float)(2*d) / 128.0f);
    float ang = (float)pos[t] * inv;
    cost[i] = cosf(ang);
    sint[i] = sinf(ang);
  }
}

#define GBAR __builtin_amdgcn_s_barrier()
#define LGKM0 do{ asm volatile("s_waitcnt lgkmcnt(0)" ::: "memory"); \
                  __builtin_amdgcn_sched_barrier(0); }while(0)

// ------- GEMM 256x256 4-phase (m201 geometry): C = A[M,K]*B[N,K]^T + bias ---
#define BUF2 32768   // elems per buffer (A 16384 + B 16384)

#define AREAD2(mh, ck) do{ \
  const u16* ab = &lds[cur + aoff + (mh)*4096]; \
  afr[0] = *(const bf16x8_t*)&ab[0*1024 + (ck)]; \
  afr[1] = *(const bf16x8_t*)&ab[1*1024 + (ck)]; \
  afr[2] = *(const bf16x8_t*)&ab[2*1024 + (ck)]; \
  afr[3] = *(const bf16x8_t*)&ab[3*1024 + (ck)]; }while(0)

#define BREAD2(ck) do{ \
  const u16* bb = &lds[cur + boff]; \
  bfr[0] = *(const bf16x8_t*)&bb[0*1024 + (ck)]; \
  bfr[1] = *(const bf16x8_t*)&bb[1*1024 + (ck)]; \
  bfr[2] = *(const bf16x8_t*)&bb[2*1024 + (ck)]; \
  bfr[3] = *(const bf16x8_t*)&bb[3*1024 + (ck)]; }while(0)

#define MM16(mh) do{ \
  _Pragma("unroll") \
  for (int mi=0; mi<4; ++mi){ \
    _Pragma("unroll") \
    for (int n=0; n<4; ++n) \
      acc[(mh)*4+mi][n] = __builtin_amdgcn_mfma_f32_16x16x32_bf16(afr[mi], bfr[n], acc[(mh)*4+mi][n],0,0,0); \
  } }while(0)

template<bool OUT_BF16>
__global__ __launch_bounds__(512, 2)
void gemm_t2(const u16* __restrict__ A, const u16* __restrict__ B,
             const float* __restrict__ bias, u16* __restrict__ Cb,
             float* __restrict__ Cf, int K, int N)
{
  __shared__ u16 lds[2*BUF2];
  const int tid = threadIdx.x, lane = tid & 63, w = tid >> 6;
  const int l15 = lane & 15, l4 = lane >> 4;
  const int wm = w >> 2, wn = w & 3;

  const int nwg = gridDim.x * gridDim.y;
  int flat = blockIdx.y * gridDim.x + blockIdx.x;
  flat = (flat & 7) * (nwg >> 3) + (flat >> 3);
  const int bx = flat % gridDim.x, by = flat / gridDim.x;
  const int bm = by * 256, bn = bx * 256;

  const int srow = w*8 + (lane >> 3);
  const int swc  = ((lane & 7) ^ (lane >> 3)) * 8;
  const u16* pAlo = A + (size_t)(bm +       srow)*K + swc;
  const u16* pAhi = A + (size_t)(bm + 128 + srow)*K + swc;
  const u16* pBlo = B + (size_t)(bn +       srow)*K + swc;
  const u16* pBhi = B + (size_t)(bn + 128 + srow)*K + swc;
  const size_t j64 = (size_t)64*K;
  const int wu = (w*8)*64;

  const int cA0 = ((0 + l4) ^ (l15 & 7)) * 8;
  const int cA1 = ((4 + l4) ^ (l15 & 7)) * 8;
  const int aoff = (wm*128 + l15) * 64;
  const int boff = 16384 + (wn*64 + l15) * 64;

  f32x4_t acc[8][4] = {};
  const int KT = K >> 6;

  gload16(pAlo,       &lds[0     + wu]);  gload16(pAlo + j64, &lds[4096  + wu]);
  gload16(pAhi,       &lds[8192  + wu]);  gload16(pAhi + j64, &lds[12288 + wu]);
  gload16(pBlo,       &lds[16384 + wu]);  gload16(pBlo + j64, &lds[20480 + wu]);
  gload16(pBhi,       &lds[24576 + wu]);  gload16(pBhi + j64, &lds[28672 + wu]);
  pAlo += 64; pAhi += 64; pBlo += 64; pBhi += 64;
  asm volatile("s_waitcnt vmcnt(0)" ::: "memory");
  GBAR;

  for (int t = 0; t < KT; ++t){
    const int cur = (t & 1) * BUF2;
    const int nxt = ((t + 1) & 1) * BUF2;
    const bool st = (t + 1 < KT);
    bf16x8_t afr[4], bfr[4];

    BREAD2(cA0); AREAD2(0, cA0);
    if (st){
      gload16(pAlo,       &lds[nxt + 0     + wu]);
      gload16(pAlo + j64, &lds[nxt + 4096  + wu]);
      gload16(pAhi,       &lds[nxt + 8192  + wu]);
      gload16(pAhi + j64, &lds[nxt + 12288 + wu]);
    }
    GBAR; LGKM0;
    __builtin_amdgcn_s_setprio(1); MM16(0); __builtin_amdgcn_s_setprio(0);
    GBAR;

    AREAD2(1, cA0);
    if (st){
      gload16(pBlo,       &lds[nxt + 16384 + wu]);
      gload16(pBlo + j64, &lds[nxt + 20480 + wu]);
      gload16(pBhi,       &lds[nxt + 24576 + wu]);
      gload16(pBhi + j64, &lds[nxt + 28672 + wu]);
      pAlo += 64; pAhi += 64; pBlo += 64; pBhi += 64;
    }
    GBAR; LGKM0;
    __builtin_amdgcn_s_setprio(1); MM16(1); __builtin_amdgcn_s_setprio(0);
    GBAR;

    BREAD2(cA1); AREAD2(0, cA1);
    GBAR; LGKM0;
    __builtin_amdgcn_s_setprio(1); MM16(0); __builtin_amdgcn_s_setprio(0);
    GBAR;

    AREAD2(1, cA1);
    GBAR; LGKM0;
    __builtin_amdgcn_s_setprio(1); MM16(1); __builtin_amdgcn_s_setprio(0);
    if (st) asm volatile("s_waitcnt vmcnt(0)" ::: "memory");
    GBAR;
  }

  #pragma unroll
  for (int m=0;m<8;m++){
    #pragma unroll
    for (int n=0;n<4;n++){
      #pragma unroll
      for (int j=0;j<4;j++){
        int row = bm + wm*128 + (m>>2)*64 + (m&3)*16 + l4*4 + j;
        int col = bn + wn*64 + n*16 + l15;
        float v = acc[m][n][j] + bias[col];
        if constexpr (OUT_BF16) Cb[(size_t)row*N + col] = f2bf(v);
        else                    Cf[(size_t)row*N + col] = v;
      }
    }
  }
}

// ------- GEMM 256x128 2-phase tri-buffer (full-fill O-proj variant) ---------
// 512 thr / 8 waves (4M x 2N), wave owns 64x64. BK=64.
// LDS: 3 bufs x (A 256x64 + B 128x64) = 3 x 48KB = 144 KB.
// Stage t+2 split 3/3 across the 2 phases; counted vmcnt(6) at tile end (r7).
#define BUFK 24576   // elems per buffer (A 16384 + B 8192)

#define KMREAD(ck) do{ \
  afr[0] = *(const bf16x8_t*)&lds[cur + aoff + 0*1024 + (ck)]; \
  afr[1] = *(const bf16x8_t*)&lds[cur + aoff + 1*1024 + (ck)]; \
  afr[2] = *(const bf16x8_t*)&lds[cur + aoff + 2*1024 + (ck)]; \
  afr[3] = *(const bf16x8_t*)&lds[cur + aoff + 3*1024 + (ck)]; \
  bfr[0] = *(const bf16x8_t*)&lds[cur + boff + 0*1024 + (ck)]; \
  bfr[1] = *(const bf16x8_t*)&lds[cur + boff + 1*1024 + (ck)]; \
  bfr[2] = *(const bf16x8_t*)&lds[cur + boff + 2*1024 + (ck)]; \
  bfr[3] = *(const bf16x8_t*)&lds[cur + boff + 3*1024 + (ck)]; }while(0)

#define MM16KM do{ \
  _Pragma("unroll") \
  for (int mi=0; mi<4; ++mi){ \
    _Pragma("unroll") \
    for (int n=0; n<4; ++n) \
      acc[mi][n] = __builtin_amdgcn_mfma_f32_16x16x32_bf16(afr[mi], bfr[n], acc[mi][n],0,0,0); \
  } }while(0)

template<bool OUT_BF16>
__global__ __launch_bounds__(512, 2)
void gemm_km(const u16* __restrict__ A, const u16* __restrict__ B,
             const float* __restrict__ bias, u16* __restrict__ Cb,
             float* __restrict__ Cf, int K, int N)
{
  __shared__ u16 lds[3*BUFK];
  const int tid = threadIdx.x, lane = tid & 63, w = tid >> 6;
  const int l15 = lane & 15, l4 = lane >> 4;
  const int wm = w >> 1, wn = w & 1;

  const int nwg = gridDim.x * gridDim.y;   // 256 (%8==0)
  int flat = blockIdx.y * gridDim.x + blockIdx.x;
  flat = (flat & 7) * (nwg >> 3) + (flat >> 3);
  const int bx = flat % gridDim.x, by = flat / gridDim.x;
  const int bm = by * 256, bn = bx * 128;

  const int srow = w*8 + (lane >> 3);
  const int swc  = ((lane & 7) ^ (lane >> 3)) * 8;
  const u16* pA = A + (size_t)(bm + srow)*K + swc;
  const u16* pB = B + (size_t)(bn + srow)*K + swc;
  const size_t j64 = (size_t)64*K;
  const int wu = (w*8)*64;

  const int cA0 = ((0 + l4) ^ (l15 & 7)) * 8;
  const int cA1 = ((4 + l4) ^ (l15 & 7)) * 8;
  const int aoff = (wm*64 + l15) * 64;           // + mi*1024
  const int boff = 16384 + (wn*64 + l15) * 64;   // + n*1024

  f32x4_t acc[4][4] = {};
  const int KT = K >> 6;

  // prologue: tile 0 -> buf0, tile 1 -> buf1 (6 loads each)
  gload16(pA + 0*j64,      &lds[0*4096 + wu]);
  gload16(pA + 1*j64,      &lds[1*4096 + wu]);
  gload16(pA + 2*j64,      &lds[2*4096 + wu]);
  gload16(pA + 3*j64,      &lds[3*4096 + wu]);
  gload16(pB + 0*j64,      &lds[16384 + 0*4096 + wu]);
  gload16(pB + 1*j64,      &lds[16384 + 1*4096 + wu]);
  gload16(pA + 64 + 0*j64, &lds[BUFK + 0*4096 + wu]);
  gload16(pA + 64 + 1*j64, &lds[BUFK + 1*4096 + wu]);
  gload16(pA + 64 + 2*j64, &lds[BUFK + 2*4096 + wu]);
  gload16(pA + 64 + 3*j64, &lds[BUFK + 3*4096 + wu]);
  gload16(pB + 64 + 0*j64, &lds[BUFK + 16384 + 0*4096 + wu]);
  gload16(pB + 64 + 1*j64, &lds[BUFK + 16384 + 1*4096 + wu]);
  pA += 128; pB += 128;
  asm volatile("s_waitcnt vmcnt(6)" ::: "memory");   // tile 0 landed
  GBAR;

  for (int t = 0; t < KT; ++t){
    const int cur = (t % 3) * BUFK;
    const int sb  = ((t + 2) % 3) * BUFK;
    const bool st = (t + 2 < KT);
    bf16x8_t afr[4], bfr[4];

    // ph0 (kk=0) | stage A chunks 0-2 of t+2
    KMREAD(cA0);
    if (st){
      gload16(pA + 0*j64, &lds[sb + 0*4096 + wu]);
      gload16(pA + 1*j64, &lds[sb + 1*4096 + wu]);
      gload16(pA + 2*j64, &lds[sb + 2*4096 + wu]);
    }
    GBAR; LGKM0;
    __builtin_amdgcn_s_setprio(1); MM16KM; __builtin_amdgcn_s_setprio(0);
    GBAR;

    // ph1 (kk=1) | stage A chunk 3 + B chunks of t+2; counted vmcnt
    KMREAD(cA1);
    if (st){
      gload16(pA + 3*j64, &lds[sb + 3*4096 + wu]);
      gload16(pB + 0*j64, &lds[sb + 16384 + 0*4096 + wu]);
      gload16(pB + 1*j64, &lds[sb + 16384 + 1*4096 + wu]);
      pA += 64; pB += 64;
    }
    GBAR; LGKM0;
    __builtin_amdgcn_s_setprio(1); MM16KM; __builtin_amdgcn_s_setprio(0);
    if (st)              asm volatile("s_waitcnt vmcnt(6)" ::: "memory");
    else if (t + 1 < KT) asm volatile("s_waitcnt vmcnt(0)" ::: "memory");
    GBAR;
  }

  #pragma unroll
  for (int mi=0;mi<4;mi++){
    #pragma unroll
    for (int n=0;n<4;n++){
      #pragma unroll
      for (int j=0;j<4;j++){
        int row = bm + wm*64 + mi*16 + l4*4 + j;
        int col = bn + wn*64 + n*16 + l15;
        float v = acc[mi][n][j] + bias[col];
        if constexpr (OUT_BF16) Cb[(size_t)row*N + col] = f2bf(v);
        else                    Cf[(size_t)row*N + col] = v;
      }
    }
  }
}

// ---------------- RoPE in-place on q (heads 0..31) and k (heads 32..39) -----
__global__ void rope_kernel(u16* __restrict__ qkv, const float* __restrict__ cost,
                            const float* __restrict__ sint){
  int i = blockIdx.x*blockDim.x + threadIdx.x;
  int t = i / 2560;
  int r = i % 2560;
  int h = r >> 6, d = r & 63;
  int base = (h < 32) ? h*128 : (4096 + (h-32)*128);
  size_t p1 = (size_t)t*ROWQKV + base + d;
  float x1 = bf2f(qkv[p1]), x2 = bf2f(qkv[p1+64]);
  float c = cost[(t<<6)+d], s = sint[(t<<6)+d];
  qkv[p1]    = f2bf(x1*c - x2*s);
  qkv[p1+64] = f2bf(x2*c + x1*s);
}

// ---------------- flash attention: block = (head, 64-row q tile) ------------
#define VOFF 16384
#define POFF 24576

__global__ __launch_bounds__(256)
void attn_kernel(const u16* __restrict__ qkv, u16* __restrict__ attn_o)
{
  __shared__ u16 lds[28672];   // 56 KB
  const int tid = threadIdx.x, lane = tid&63, wid = tid>>6;
  const int l15 = lane&15, l4 = lane>>4;
  const int l7 = l15 & 7;
  const int h  = blockIdx.x & 31;
  const int qt = 31 - (blockIdx.x >> 5);       // heavy tiles first
  const int q0 = qt * 64;
  const int kvh = h >> 2;
  const u16* Qg = qkv + h*128;
  const u16* Kg = qkv + 4096 + kvh*128;
  const u16* Vg = qkv + 5120 + kvh*128;

  bf16x8_t qf[4];
  {
    size_t qrow = (size_t)(q0 + wid*16 + l15);
    #pragma unroll
    for (int kk=0;kk<4;kk++)
      qf[kk] = *(const bf16x8_t*)(Qg + qrow*ROWQKV + kk*32 + l4*8);
  }
  float mrow[4] = {-1e30f,-1e30f,-1e30f,-1e30f};
  float lrow[4] = {0.f,0.f,0.f,0.f};
  f32x4_t oacc[8] = {};
  const float scale = 0.08838834764831845f;  // 1/sqrt(128)

  const u16* ksrc[4];
  int kls[4];
  #pragma unroll
  for (int i=0;i<4;i++){
    const int c = wid*4 + i;
    ksrc[i] = Kg + (size_t)((c&7)*8 + (lane>>3))*ROWQKV
               + (c>>3)*64 + ((lane&7)^(lane>>3))*8;
    kls[i] = c*512;
  }
  const int kvp = tid & 31;
  const int vd0 = (tid >> 5) * 16;
  uint4 rv[4];

  #pragma unroll
  for (int i=0;i<4;i++) gload16(ksrc[i], &lds[kls[i]]);
  #pragma unroll
  for (int i=0;i<4;i++) ksrc[i] += (size_t)64*ROWQKV;
  {
    const u16* va = Vg + (size_t)(2*kvp)*ROWQKV + vd0;
    rv[0] = *(const uint4*)va;            rv[1] = *(const uint4*)(va + 8);
    rv[2] = *(const uint4*)(va + ROWQKV); rv[3] = *(const uint4*)(va + ROWQKV + 8);
  }
  __syncthreads();
  {
    const u16* ra = (const u16*)&rv[0]; const u16* rb = (const u16*)&rv[2];
    #pragma unroll
    for (int e=0;e<8;e++)
      *(uint32_t*)&lds[VOFF + (vd0+e)*64 + ((kvp>>2)^(e&7))*8 + 2*(kvp&3)]
          = (uint32_t)ra[e] | ((uint32_t)rb[e] << 16);
    ra = (const u16*)&rv[1]; rb = (const u16*)&rv[3];
    #pragma unroll
    for (int e=0;e<8;e++)
      *(uint32_t*)&lds[VOFF + (vd0+8+e)*64 + ((kvp>>2)^(e&7))*8 + 2*(kvp&3)]
          = (uint32_t)ra[e] | ((uint32_t)rb[e] << 16);
  }
  __syncthreads();

  for (int kt = 0; kt <= qt; ++kt){
    const int kv0 = kt * 64;
    const int kcur = (kt & 1) * 8192;
    const bool pre = (kt < qt);
    if (pre){
      const int knxt = ((kt+1) & 1) * 8192;
      #pragma unroll
      for (int i=0;i<4;i++) gload16(ksrc[i], &lds[knxt + kls[i]]);
      #pragma unroll
      for (int i=0;i<4;i++) ksrc[i] += (size_t)64*ROWQKV;
      const u16* va = Vg + (size_t)(kv0 + 64 + 2*kvp)*ROWQKV + vd0;
      rv[0] = *(const uint4*)va;            rv[1] = *(const uint4*)(va + 8);
      rv[2] = *(const uint4*)(va + ROWQKV); rv[3] = *(const uint4*)(va + ROWQKV + 8);
    }

    f32x4_t sacc[4] = {};
    #pragma unroll
    for (int n=0;n<4;n++){
      #pragma unroll
      for (int kk=0;kk<4;kk++){
        bf16x8_t kf = *(const bf16x8_t*)&lds[kcur + (kk>>1)*4096
                        + (n*16+l15)*64 + (((kk&1)*4 + l4) ^ l7)*8];
        sacc[n] = __builtin_amdgcn_mfma_f32_16x16x32_bf16(qf[kk], kf, sacc[n], 0,0,0);
      }
    }
    float sv[4][4];
    float pmax[4] = {-1e30f,-1e30f,-1e30f,-1e30f};
    bool diag = (kt == qt);
    #pragma unroll
    for (int n=0;n<4;n++){
      int kvcol = kv0 + n*16 + l15;
      #pragma unroll
      for (int j=0;j<4;j++){
        float s = sacc[n][j] * scale;
        int qrow = q0 + wid*16 + l4*4 + j;
        if (diag && kvcol > qrow) s = -1e30f;
        sv[n][j] = s;
        pmax[j] = fmaxf(pmax[j], s);
      }
    }
    #pragma unroll
    for (int off=1; off<16; off<<=1){
      #pragma unroll
      for (int j=0;j<4;j++)
        pmax[j] = fmaxf(pmax[j], __shfl_xor(pmax[j], off, 64));
    }
    float esc[4], rsum[4] = {0.f,0.f,0.f,0.f};
    #pragma unroll
    for (int j=0;j<4;j++){
      float mn = fmaxf(mrow[j], pmax[j]);
      esc[j] = __expf(mrow[j] - mn);
      mrow[j] = mn;
    }
    #pragma unroll
    for (int n=0;n<4;n++){
      #pragma unroll
      for (int j=0;j<4;j++){
        float p = __expf(sv[n][j] - mrow[j]);
        sv[n][j] = p;
        rsum[j] += p;
      }
    }
    #pragma unroll
    for (int off=1; off<16; off<<=1){
      #pragma unroll
      for (int j=0;j<4;j++)
        rsum[j] += __shfl_xor(rsum[j], off, 64);
    }
    #pragma unroll
    for (int j=0;j<4;j++) lrow[j] = lrow[j]*esc[j] + rsum[j];
    #pragma unroll
    for (int n=0;n<8;n++){
      #pragma unroll
      for (int j=0;j<4;j++) oacc[n][j] *= esc[j];
    }
    #pragma unroll
    for (int n=0;n<4;n++){
      #pragma unroll
      for (int j=0;j<4;j++)
        lds[POFF + (wid*16 + l4*4 + j)*64
            + (((n*2 + (l15>>3)) ^ ((l4*4+j)&7))*8) + l7] = f2bf(sv[n][j]);
    }
    #pragma unroll
    for (int kk=0;kk<2;kk++){
      const int blk = ((kk*4 + l4) ^ l7)*8;
      bf16x8_t pf = *(const bf16x8_t*)&lds[POFF + (wid*16 + l15)*64 + blk];
      #pragma unroll
      for (int n=0;n<8;n++){
        bf16x8_t vf = *(const bf16x8_t*)&lds[VOFF + (n*16 + l15)*64 + blk];
        oacc[n] = __builtin_amdgcn_mfma_f32_16x16x32_bf16(pf, vf, oacc[n], 0,0,0);
      }
    }
    __syncthreads();
    if (pre){
      const u16* ra = (const u16*)&rv[0]; const u16* rb = (const u16*)&rv[2];
      #pragma unroll
      for (int e=0;e<8;e++)
        *(uint32_t*)&lds[VOFF + (vd0+e)*64 + ((kvp>>2)^(e&7))*8 + 2*(kvp&3)]
            = (uint32_t)ra[e] | ((uint32_t)rb[e] << 16);
      ra = (const u16*)&rv[1]; rb = (const u16*)&rv[3];
      #pragma unroll
      for (int e=0;e<8;e++)
        *(uint32_t*)&lds[VOFF + (vd0+8+e)*64 + ((kvp>>2)^(e&7))*8 + 2*(kvp&3)]
            = (uint32_t)ra[e] | ((uint32_t)rb[e] << 16);
    }
    __syncthreads();
  }

  #pragma unroll
  for (int n=0;n<8;n++){
    #pragma unroll
    for (int j=0;j<4;j++){
      int qrow = q0 + wid*16 + l4*4 + j;
      int col  = h*128 + n*16 + l15;
      attn_o[(size_t)qrow*HID + col] = f2bf(oacc[n][j] / lrow[j]);
    }
  }
}

// ---------------- launcher ----------------
extern "C" void kernel_launch(void* const* d_in, const int* in_sizes, int n_in,
                              void* d_out, int out_size, void* d_ws, size_t ws_size,
                              hipStream_t stream)
{
  const float* hs = (const float*)d_in[0];
  const int*  pos = (const int*)d_in[1];
  const float* Wq = (const float*)d_in[2];
  const float* bq = (const float*)d_in[3];
  const float* Wk = (const float*)d_in[4];
  const float* bk = (const float*)d_in[5];
  const float* Wv = (const float*)d_in[6];
  const float* bv = (const float*)d_in[7];
  const float* Wo = (const float*)d_in[8];
  const float* bo = (const float*)d_in[9];
  float* out = (float*)d_out;

  char* ws = (char*)d_ws;
  u16* hs_bf   = (u16*)ws;  ws += (size_t)2048*4096*2;
  u16* Wqkv_bf = (u16*)ws;  ws += (size_t)6144*4096*2;
  u16* Wo_bf   = (u16*)ws;  ws += (size_t)4096*4096*2;
  u16* qkv     = (u16*)ws;  ws += (size_t)2048*6144*2;
  u16* attn_b  = (u16*)ws;  ws += (size_t)2048*4096*2;
  float* bqkv  = (float*)ws; ws += (size_t)6144*4;
  float* cost  = (float*)ws; ws += (size_t)2048*64*4;
  float* sint  = (float*)ws; ws += (size_t)2048*64*4;

  {
    int n8 = 2048*4096/8;
    cvt_kernel<<<(n8+255)/256, 256, 0, stream>>>(hs, hs_bf, n8);
    n8 = 4096*4096/8;
    cvt_kernel<<<(n8+255)/256, 256, 0, stream>>>(Wq, Wqkv_bf, n8);
    n8 = 1024*4096/8;
    cvt_kernel<<<(n8+255)/256, 256, 0, stream>>>(Wk, Wqkv_bf + (size_t)4096*4096, n8);
    cvt_kernel<<<(n8+255)/256, 256, 0, stream>>>(Wv, Wqkv_bf + (size_t)5120*4096, n8);
    n8 = 4096*4096/8;
    cvt_kernel<<<(n8+255)/256, 256, 0, stream>>>(Wo, Wo_bf, n8);
  }
  setup_kernel<<<(T_SEQ*64 + 255)/256, 256, 0, stream>>>(bq, bk, bv, pos, bqkv, cost, sint);

  // QKV projection: [2048,6144] — 256x256 tiles, grid 24x8 = 192 blocks
  gemm_t2<true><<<dim3(6144/256, 2048/256), 512, 0, stream>>>(hs_bf, Wqkv_bf, bqkv, qkv, nullptr, 4096, 6144);
  // RoPE on q,k
  rope_kernel<<<(T_SEQ*40*64)/256, 256, 0, stream>>>(qkv, cost, sint);
  // attention
  attn_kernel<<<1024, 256, 0, stream>>>(qkv, attn_b);
  // output projection: [2048,4096] — 256x128 tiles, grid 32x8 = 256 blocks (full fill)
  gemm_km<false><<<dim3(4096/128, 2048/256), 512, 0, stream>>>(attn_b, Wo_bf, bo, nullptr, out, 4096, 4096);
}

// Round 11
// 341.458 us; speedup vs baseline: 2.7061x; 1.0459x over previous
//
#include <hip/hip_runtime.h>
#include <stdint.h>

typedef unsigned short u16;
typedef __bf16 bf16x8_t __attribute__((ext_vector_type(8)));
typedef float f32x4_t __attribute__((ext_vector_type(4)));

#define T_SEQ 2048
#define HID 4096
#define ROWQKV 6144

__device__ __forceinline__ float bf2f(u16 x){ return __uint_as_float(((uint32_t)x)<<16); }
__device__ __forceinline__ u16 f2bf(float f){
  uint32_t u = __float_as_uint(f);
  return (u16)((u + 0x7fffu + ((u>>16)&1u)) >> 16);
}

__device__ __forceinline__ void gload16(const void* g, void* l){
  __builtin_amdgcn_global_load_lds(
      (const __attribute__((address_space(1))) uint32_t*)g,
      (__attribute__((address_space(3))) uint32_t*)l, 16, 0, 0);
}

// ---------------- fp32 -> bf16 conversion (8 elems / thread) ----------------
__global__ void cvt_kernel(const float* __restrict__ src, u16* __restrict__ dst, int n8){
  int i = blockIdx.x*blockDim.x + threadIdx.x;
  if (i >= n8) return;
  const float4* s = (const float4*)src;
  float4 a = s[2*i], b = s[2*i+1];
  union { u16 u[8]; uint4 v; } o;
  o.u[0]=f2bf(a.x); o.u[1]=f2bf(a.y); o.u[2]=f2bf(a.z); o.u[3]=f2bf(a.w);
  o.u[4]=f2bf(b.x); o.u[5]=f2bf(b.y); o.u[6]=f2bf(b.z); o.u[7]=f2bf(b.w);
  ((uint4*)dst)[i] = o.v;
}

// ---------------- bias concat + rope tables ----------------
__global__ void setup_kernel(const float* __restrict__ bq, const float* __restrict__ bk,
                             const float* __restrict__ bv, const int* __restrict__ pos,
                             float* __restrict__ bqkv, float* __restrict__ cost,
                             float* __restrict__ sint){
  int i = blockIdx.x*blockDim.x + threadIdx.x;
  if (i < 6144) bqkv[i] = (i<4096) ? bq[i] : ((i<5120) ? bk[i-4096] : bv[i-5120]);
  if (i < T_SEQ*64){
    int t = i >> 6, d = i & 63;
    float inv = powf(10000.0f, -(float)(2*d) / 128.0f);
    float ang = (float)pos[t] * inv;
    cost[i] = cosf(ang);
    sint[i] = sinf(ang);
  }
}

#define GBAR __builtin_amdgcn_s_barrier()
#define LGKM0 do{ asm volatile("s_waitcnt lgkmcnt(0)" ::: "memory"); \
                  __builtin_amdgcn_sched_barrier(0); }while(0)

// ------- GEMM 256x192 4-phase (full-fill QKV): C = A[M,K]*B[N,K]^T + bias ---
// 512 thr / 8 waves (2M x 4N), wave owns 128x48. BK=64. Grid = exactly 256.
// LDS: 2 bufs x (A 256x64 + B 192x64) u16 = 2 x 57344 B = 112 KB.
// Same phases/barriers/swizzle/vmcnt as the r8-verified gemm_t2; only N-extent
// and B staging (3 gloads) change.
#define BUF6 28672   // elems per buffer (A 16384 + B 12288)

#define AREAD6(mh, ck) do{ \
  const u16* ab = &lds[cur + aoff + (mh)*4096]; \
  afr[0] = *(const bf16x8_t*)&ab[0*1024 + (ck)]; \
  afr[1] = *(const bf16x8_t*)&ab[1*1024 + (ck)]; \
  afr[2] = *(const bf16x8_t*)&ab[2*1024 + (ck)]; \
  afr[3] = *(const bf16x8_t*)&ab[3*1024 + (ck)]; }while(0)

#define BREAD6(ck) do{ \
  const u16* bb = &lds[cur + boff]; \
  bfr[0] = *(const bf16x8_t*)&bb[0*1024 + (ck)]; \
  bfr[1] = *(const bf16x8_t*)&bb[1*1024 + (ck)]; \
  bfr[2] = *(const bf16x8_t*)&bb[2*1024 + (ck)]; }while(0)

#define MM12(mh) do{ \
  _Pragma("unroll") \
  for (int mi=0; mi<4; ++mi){ \
    _Pragma("unroll") \
    for (int n=0; n<3; ++n) \
      acc[(mh)*4+mi][n] = __builtin_amdgcn_mfma_f32_16x16x32_bf16(afr[mi], bfr[n], acc[(mh)*4+mi][n],0,0,0); \
  } }while(0)

__global__ __launch_bounds__(512, 2)
void gemm_qkv(const u16* __restrict__ A, const u16* __restrict__ B,
              const float* __restrict__ bias, u16* __restrict__ Cb,
              int K, int N)
{
  __shared__ u16 lds[2*BUF6];
  const int tid = threadIdx.x, lane = tid & 63, w = tid >> 6;
  const int l15 = lane & 15, l4 = lane >> 4;
  const int wm = w >> 2, wn = w & 3;

  const int nwg = gridDim.x * gridDim.y;   // 256
  int flat = blockIdx.y * gridDim.x + blockIdx.x;
  flat = (flat & 7) * (nwg >> 3) + (flat >> 3);
  const int bx = flat % gridDim.x, by = flat / gridDim.x;
  const int bm = by * 256, bn = bx * 192;

  const int srow = w*8 + (lane >> 3);
  const int swc  = ((lane & 7) ^ (lane >> 3)) * 8;
  const u16* pA = A + (size_t)(bm + srow)*K + swc;
  const u16* pB = B + (size_t)(bn + srow)*K + swc;
  const size_t j64 = (size_t)64*K;
  const int wu = w*512;

  const int cA0 = ((0 + l4) ^ (l15 & 7)) * 8;
  const int cA1 = ((4 + l4) ^ (l15 & 7)) * 8;
  const int aoff = (wm*128 + l15) * 64;
  const int boff = 16384 + (wn*48 + l15) * 64;

  f32x4_t acc[8][3] = {};
  const int KT = K >> 6;

  // prologue: tile 0 -> buf0 (A 4 gloads + B 3 gloads)
  gload16(pA + 0*j64, &lds[0     + wu]);
  gload16(pA + 1*j64, &lds[4096  + wu]);
  gload16(pA + 2*j64, &lds[8192  + wu]);
  gload16(pA + 3*j64, &lds[12288 + wu]);
  gload16(pB + 0*j64, &lds[16384 + wu]);
  gload16(pB + 1*j64, &lds[20480 + wu]);
  gload16(pB + 2*j64, &lds[24576 + wu]);
  pA += 64; pB += 64;
  asm volatile("s_waitcnt vmcnt(0)" ::: "memory");
  GBAR;

  for (int t = 0; t < KT; ++t){
    const int cur = (t & 1) * BUF6;
    const int nxt = ((t + 1) & 1) * BUF6;
    const bool st = (t + 1 < KT);
    bf16x8_t afr[4], bfr[3];

    // ph0: B(kk0) + A(mh0,kk0) | stage A(t+1)
    BREAD6(cA0); AREAD6(0, cA0);
    if (st){
      gload16(pA + 0*j64, &lds[nxt + 0     + wu]);
      gload16(pA + 1*j64, &lds[nxt + 4096  + wu]);
      gload16(pA + 2*j64, &lds[nxt + 8192  + wu]);
      gload16(pA + 3*j64, &lds[nxt + 12288 + wu]);
    }
    GBAR; LGKM0;
    __builtin_amdgcn_s_setprio(1); MM12(0); __builtin_amdgcn_s_setprio(0);
    GBAR;

    // ph1: A(mh1,kk0), B held | stage B(t+1)
    AREAD6(1, cA0);
    if (st){
      gload16(pB + 0*j64, &lds[nxt + 16384 + wu]);
      gload16(pB + 1*j64, &lds[nxt + 20480 + wu]);
      gload16(pB + 2*j64, &lds[nxt + 24576 + wu]);
      pA += 64; pB += 64;
    }
    GBAR; LGKM0;
    __builtin_amdgcn_s_setprio(1); MM12(1); __builtin_amdgcn_s_setprio(0);
    GBAR;

    // ph2: B(kk1) + A(mh0,kk1)
    BREAD6(cA1); AREAD6(0, cA1);
    GBAR; LGKM0;
    __builtin_amdgcn_s_setprio(1); MM12(0); __builtin_amdgcn_s_setprio(0);
    GBAR;

    // ph3: A(mh1,kk1), B held | tile-end drain
    AREAD6(1, cA1);
    GBAR; LGKM0;
    __builtin_amdgcn_s_setprio(1); MM12(1); __builtin_amdgcn_s_setprio(0);
    if (st) asm volatile("s_waitcnt vmcnt(0)" ::: "memory");
    GBAR;
  }

  #pragma unroll
  for (int m=0;m<8;m++){
    #pragma unroll
    for (int n=0;n<3;n++){
      #pragma unroll
      for (int j=0;j<4;j++){
        int row = bm + wm*128 + (m>>2)*64 + (m&3)*16 + l4*4 + j;
        int col = bn + wn*48 + n*16 + l15;
        Cb[(size_t)row*N + col] = f2bf(acc[m][n][j] + bias[col]);
      }
    }
  }
}

// ------- GEMM 256x128 2-phase tri-buffer (full-fill O-proj variant) ---------
#define BUFK 24576   // elems per buffer (A 16384 + B 8192)

#define KMREAD(ck) do{ \
  afr[0] = *(const bf16x8_t*)&lds[cur + aoff + 0*1024 + (ck)]; \
  afr[1] = *(const bf16x8_t*)&lds[cur + aoff + 1*1024 + (ck)]; \
  afr[2] = *(const bf16x8_t*)&lds[cur + aoff + 2*1024 + (ck)]; \
  afr[3] = *(const bf16x8_t*)&lds[cur + aoff + 3*1024 + (ck)]; \
  bfr[0] = *(const bf16x8_t*)&lds[cur + boff + 0*1024 + (ck)]; \
  bfr[1] = *(const bf16x8_t*)&lds[cur + boff + 1*1024 + (ck)]; \
  bfr[2] = *(const bf16x8_t*)&lds[cur + boff + 2*1024 + (ck)]; \
  bfr[3] = *(const bf16x8_t*)&lds[cur + boff + 3*1024 + (ck)]; }while(0)

#define MM16KM do{ \
  _Pragma("unroll") \
  for (int mi=0; mi<4; ++mi){ \
    _Pragma("unroll") \
    for (int n=0; n<4; ++n) \
      acc[mi][n] = __builtin_amdgcn_mfma_f32_16x16x32_bf16(afr[mi], bfr[n], acc[mi][n],0,0,0); \
  } }while(0)

__global__ __launch_bounds__(512, 2)
void gemm_km(const u16* __restrict__ A, const u16* __restrict__ B,
             const float* __restrict__ bias, float* __restrict__ Cf,
             int K, int N)
{
  __shared__ u16 lds[3*BUFK];
  const int tid = threadIdx.x, lane = tid & 63, w = tid >> 6;
  const int l15 = lane & 15, l4 = lane >> 4;
  const int wm = w >> 1, wn = w & 1;

  const int nwg = gridDim.x * gridDim.y;   // 256
  int flat = blockIdx.y * gridDim.x + blockIdx.x;
  flat = (flat & 7) * (nwg >> 3) + (flat >> 3);
  const int bx = flat % gridDim.x, by = flat / gridDim.x;
  const int bm = by * 256, bn = bx * 128;

  const int srow = w*8 + (lane >> 3);
  const int swc  = ((lane & 7) ^ (lane >> 3)) * 8;
  const u16* pA = A + (size_t)(bm + srow)*K + swc;
  const u16* pB = B + (size_t)(bn + srow)*K + swc;
  const size_t j64 = (size_t)64*K;
  const int wu = w*512;

  const int cA0 = ((0 + l4) ^ (l15 & 7)) * 8;
  const int cA1 = ((4 + l4) ^ (l15 & 7)) * 8;
  const int aoff = (wm*64 + l15) * 64;
  const int boff = 16384 + (wn*64 + l15) * 64;

  f32x4_t acc[4][4] = {};
  const int KT = K >> 6;

  gload16(pA + 0*j64,      &lds[0*4096 + wu]);
  gload16(pA + 1*j64,      &lds[1*4096 + wu]);
  gload16(pA + 2*j64,      &lds[2*4096 + wu]);
  gload16(pA + 3*j64,      &lds[3*4096 + wu]);
  gload16(pB + 0*j64,      &lds[16384 + 0*4096 + wu]);
  gload16(pB + 1*j64,      &lds[16384 + 1*4096 + wu]);
  gload16(pA + 64 + 0*j64, &lds[BUFK + 0*4096 + wu]);
  gload16(pA + 64 + 1*j64, &lds[BUFK + 1*4096 + wu]);
  gload16(pA + 64 + 2*j64, &lds[BUFK + 2*4096 + wu]);
  gload16(pA + 64 + 3*j64, &lds[BUFK + 3*4096 + wu]);
  gload16(pB + 64 + 0*j64, &lds[BUFK + 16384 + 0*4096 + wu]);
  gload16(pB + 64 + 1*j64, &lds[BUFK + 16384 + 1*4096 + wu]);
  pA += 128; pB += 128;
  asm volatile("s_waitcnt vmcnt(6)" ::: "memory");
  GBAR;

  for (int t = 0; t < KT; ++t){
    const int cur = (t % 3) * BUFK;
    const int sb  = ((t + 2) % 3) * BUFK;
    const bool st = (t + 2 < KT);
    bf16x8_t afr[4], bfr[4];

    KMREAD(cA0);
    if (st){
      gload16(pA + 0*j64, &lds[sb + 0*4096 + wu]);
      gload16(pA + 1*j64, &lds[sb + 1*4096 + wu]);
      gload16(pA + 2*j64, &lds[sb + 2*4096 + wu]);
    }
    GBAR; LGKM0;
    __builtin_amdgcn_s_setprio(1); MM16KM; __builtin_amdgcn_s_setprio(0);
    GBAR;

    KMREAD(cA1);
    if (st){
      gload16(pA + 3*j64, &lds[sb + 3*4096 + wu]);
      gload16(pB + 0*j64, &lds[sb + 16384 + 0*4096 + wu]);
      gload16(pB + 1*j64, &lds[sb + 16384 + 1*4096 + wu]);
      pA += 64; pB += 64;
    }
    GBAR; LGKM0;
    __builtin_amdgcn_s_setprio(1); MM16KM; __builtin_amdgcn_s_setprio(0);
    if (st)              asm volatile("s_waitcnt vmcnt(6)" ::: "memory");
    else if (t + 1 < KT) asm volatile("s_waitcnt vmcnt(0)" ::: "memory");
    GBAR;
  }

  #pragma unroll
  for (int mi=0;mi<4;mi++){
    #pragma unroll
    for (int n=0;n<4;n++){
      #pragma unroll
      for (int j=0;j<4;j++){
        int row = bm + wm*64 + mi*16 + l4*4 + j;
        int col = bn + wn*64 + n*16 + l15;
        Cf[(size_t)row*N + col] = acc[mi][n][j] + bias[col];
      }
    }
  }
}

// ---------------- RoPE in-place on q (heads 0..31) and k (heads 32..39) -----
__global__ void rope_kernel(u16* __restrict__ qkv, const float* __restrict__ cost,
                            const float* __restrict__ sint){
  int i = blockIdx.x*blockDim.x + threadIdx.x;
  int t = i / 2560;
  int r = i % 2560;
  int h = r >> 6, d = r & 63;
  int base = (h < 32) ? h*128 : (4096 + (h-32)*128);
  size_t p1 = (size_t)t*ROWQKV + base + d;
  float x1 = bf2f(qkv[p1]), x2 = bf2f(qkv[p1+64]);
  float c = cost[(t<<6)+d], s = sint[(t<<6)+d];
  qkv[p1]    = f2bf(x1*c - x2*s);
  qkv[p1+64] = f2bf(x2*c + x1*s);
}

// ---------------- flash attention: block = (head, 64-row q tile) ------------
#define VOFF 16384
#define POFF 24576

__global__ __launch_bounds__(256)
void attn_kernel(const u16* __restrict__ qkv, u16* __restrict__ attn_o)
{
  __shared__ u16 lds[28672];   // 56 KB
  const int tid = threadIdx.x, lane = tid&63, wid = tid>>6;
  const int l15 = lane&15, l4 = lane>>4;
  const int l7 = l15 & 7;
  const int h  = blockIdx.x & 31;
  const int qt = 31 - (blockIdx.x >> 5);       // heavy tiles first
  const int q0 = qt * 64;
  const int kvh = h >> 2;
  const u16* Qg = qkv + h*128;
  const u16* Kg = qkv + 4096 + kvh*128;
  const u16* Vg = qkv + 5120 + kvh*128;

  bf16x8_t qf[4];
  {
    size_t qrow = (size_t)(q0 + wid*16 + l15);
    #pragma unroll
    for (int kk=0;kk<4;kk++)
      qf[kk] = *(const bf16x8_t*)(Qg + qrow*ROWQKV + kk*32 + l4*8);
  }
  float mrow[4] = {-1e30f,-1e30f,-1e30f,-1e30f};
  float lrow[4] = {0.f,0.f,0.f,0.f};
  f32x4_t oacc[8] = {};
  const float scale = 0.08838834764831845f;  // 1/sqrt(128)

  const u16* ksrc[4];
  int kls[4];
  #pragma unroll
  for (int i=0;i<4;i++){
    const int c = wid*4 + i;
    ksrc[i] = Kg + (size_t)((c&7)*8 + (lane>>3))*ROWQKV
               + (c>>3)*64 + ((lane&7)^(lane>>3))*8;
    kls[i] = c*512;
  }
  const int kvp = tid & 31;
  const int vd0 = (tid >> 5) * 16;
  uint4 rv[4];

  #pragma unroll
  for (int i=0;i<4;i++) gload16(ksrc[i], &lds[kls[i]]);
  #pragma unroll
  for (int i=0;i<4;i++) ksrc[i] += (size_t)64*ROWQKV;
  {
    const u16* va = Vg + (size_t)(2*kvp)*ROWQKV + vd0;
    rv[0] = *(const uint4*)va;            rv[1] = *(const uint4*)(va + 8);
    rv[2] = *(const uint4*)(va + ROWQKV); rv[3] = *(const uint4*)(va + ROWQKV + 8);
  }
  __syncthreads();
  {
    const u16* ra = (const u16*)&rv[0]; const u16* rb = (const u16*)&rv[2];
    #pragma unroll
    for (int e=0;e<8;e++)
      *(uint32_t*)&lds[VOFF + (vd0+e)*64 + ((kvp>>2)^(e&7))*8 + 2*(kvp&3)]
          = (uint32_t)ra[e] | ((uint32_t)rb[e] << 16);
    ra = (const u16*)&rv[1]; rb = (const u16*)&rv[3];
    #pragma unroll
    for (int e=0;e<8;e++)
      *(uint32_t*)&lds[VOFF + (vd0+8+e)*64 + ((kvp>>2)^(e&7))*8 + 2*(kvp&3)]
          = (uint32_t)ra[e] | ((uint32_t)rb[e] << 16);
  }
  __syncthreads();

  for (int kt = 0; kt <= qt; ++kt){
    const int kv0 = kt * 64;
    const int kcur = (kt & 1) * 8192;
    const bool pre = (kt < qt);
    if (pre){
      const int knxt = ((kt+1) & 1) * 8192;
      #pragma unroll
      for (int i=0;i<4;i++) gload16(ksrc[i], &lds[knxt + kls[i]]);
      #pragma unroll
      for (int i=0;i<4;i++) ksrc[i] += (size_t)64*ROWQKV;
      const u16* va = Vg + (size_t)(kv0 + 64 + 2*kvp)*ROWQKV + vd0;
      rv[0] = *(const uint4*)va;            rv[1] = *(const uint4*)(va + 8);
      rv[2] = *(const uint4*)(va + ROWQKV); rv[3] = *(const uint4*)(va + ROWQKV + 8);
    }

    f32x4_t sacc[4] = {};
    #pragma unroll
    for (int n=0;n<4;n++){
      #pragma unroll
      for (int kk=0;kk<4;kk++){
        bf16x8_t kf = *(const bf16x8_t*)&lds[kcur + (kk>>1)*4096
                        + (n*16+l15)*64 + (((kk&1)*4 + l4) ^ l7)*8];
        sacc[n] = __builtin_amdgcn_mfma_f32_16x16x32_bf16(qf[kk], kf, sacc[n], 0,0,0);
      }
    }
    float sv[4][4];
    float pmax[4] = {-1e30f,-1e30f,-1e30f,-1e30f};
    bool diag = (kt == qt);
    #pragma unroll
    for (int n=0;n<4;n++){
      int kvcol = kv0 + n*16 + l15;
      #pragma unroll
      for (int j=0;j<4;j++){
        float s = sacc[n][j] * scale;
        int qrow = q0 + wid*16 + l4*4 + j;
        if (diag && kvcol > qrow) s = -1e30f;
        sv[n][j] = s;
        pmax[j] = fmaxf(pmax[j], s);
      }
    }
    #pragma unroll
    for (int off=1; off<16; off<<=1){
      #pragma unroll
      for (int j=0;j<4;j++)
        pmax[j] = fmaxf(pmax[j], __shfl_xor(pmax[j], off, 64));
    }
    float esc[4], rsum[4] = {0.f,0.f,0.f,0.f};
    #pragma unroll
    for (int j=0;j<4;j++){
      float mn = fmaxf(mrow[j], pmax[j]);
      esc[j] = __expf(mrow[j] - mn);
      mrow[j] = mn;
    }
    #pragma unroll
    for (int n=0;n<4;n++){
      #pragma unroll
      for (int j=0;j<4;j++){
        float p = __expf(sv[n][j] - mrow[j]);
        sv[n][j] = p;
        rsum[j] += p;
      }
    }
    #pragma unroll
    for (int off=1; off<16; off<<=1){
      #pragma unroll
      for (int j=0;j<4;j++)
        rsum[j] += __shfl_xor(rsum[j], off, 64);
    }
    #pragma unroll
    for (int j=0;j<4;j++) lrow[j] = lrow[j]*esc[j] + rsum[j];
    #pragma unroll
    for (int n=0;n<8;n++){
      #pragma unroll
      for (int j=0;j<4;j++) oacc[n][j] *= esc[j];
    }
    #pragma unroll
    for (int n=0;n<4;n++){
      #pragma unroll
      for (int j=0;j<4;j++)
        lds[POFF + (wid*16 + l4*4 + j)*64
            + (((n*2 + (l15>>3)) ^ ((l4*4+j)&7))*8) + l7] = f2bf(sv[n][j]);
    }
    #pragma unroll
    for (int kk=0;kk<2;kk++){
      const int blk = ((kk*4 + l4) ^ l7)*8;
      bf16x8_t pf = *(const bf16x8_t*)&lds[POFF + (wid*16 + l15)*64 + blk];
      #pragma unroll
      for (int n=0;n<8;n++){
        bf16x8_t vf = *(const bf16x8_t*)&lds[VOFF + (n*16 + l15)*64 + blk];
        oacc[n] = __builtin_amdgcn_mfma_f32_16x16x32_bf16(pf, vf, oacc[n], 0,0,0);
      }
    }
    __syncthreads();
    if (pre){
      const u16* ra = (const u16*)&rv[0]; const u16* rb = (const u16*)&rv[2];
      #pragma unroll
      for (int e=0;e<8;e++)
        *(uint32_t*)&lds[VOFF + (vd0+e)*64 + ((kvp>>2)^(e&7))*8 + 2*(kvp&3)]
            = (uint32_t)ra[e] | ((uint32_t)rb[e] << 16);
      ra = (const u16*)&rv[1]; rb = (const u16*)&rv[3];
      #pragma unroll
      for (int e=0;e<8;e++)
        *(uint32_t*)&lds[VOFF + (vd0+8+e)*64 + ((kvp>>2)^(e&7))*8 + 2*(kvp&3)]
            = (uint32_t)ra[e] | ((uint32_t)rb[e] << 16);
    }
    __syncthreads();
  }

  #pragma unroll
  for (int n=0;n<8;n++){
    #pragma unroll
    for (int j=0;j<4;j++){
      int qrow = q0 + wid*16 + l4*4 + j;
      int col  = h*128 + n*16 + l15;
      attn_o[(size_t)qrow*HID + col] = f2bf(oacc[n][j] / lrow[j]);
    }
  }
}

// ---------------- launcher ----------------
extern "C" void kernel_launch(void* const* d_in, const int* in_sizes, int n_in,
                              void* d_out, int out_size, void* d_ws, size_t ws_size,
                              hipStream_t stream)
{
  const float* hs = (const float*)d_in[0];
  const int*  pos = (const int*)d_in[1];
  const float* Wq = (const float*)d_in[2];
  const float* bq = (const float*)d_in[3];
  const float* Wk = (const float*)d_in[4];
  const float* bk = (const float*)d_in[5];
  const float* Wv = (const float*)d_in[6];
  const float* bv = (const float*)d_in[7];
  const float* Wo = (const float*)d_in[8];
  const float* bo = (const float*)d_in[9];
  float* out = (float*)d_out;

  char* ws = (char*)d_ws;
  u16* hs_bf   = (u16*)ws;  ws += (size_t)2048*4096*2;
  u16* Wqkv_bf = (u16*)ws;  ws += (size_t)6144*4096*2;
  u16* Wo_bf   = (u16*)ws;  ws += (size_t)4096*4096*2;
  u16* qkv     = (u16*)ws;  ws += (size_t)2048*6144*2;
  u16* attn_b  = (u16*)ws;  ws += (size_t)2048*4096*2;
  float* bqkv  = (float*)ws; ws += (size_t)6144*4;
  float* cost  = (float*)ws; ws += (size_t)2048*64*4;
  float* sint  = (float*)ws; ws += (size_t)2048*64*4;

  {
    int n8 = 2048*4096/8;
    cvt_kernel<<<(n8+255)/256, 256, 0, stream>>>(hs, hs_bf, n8);
    n8 = 4096*4096/8;
    cvt_kernel<<<(n8+255)/256, 256, 0, stream>>>(Wq, Wqkv_bf, n8);
    n8 = 1024*4096/8;
    cvt_kernel<<<(n8+255)/256, 256, 0, stream>>>(Wk, Wqkv_bf + (size_t)4096*4096, n8);
    cvt_kernel<<<(n8+255)/256, 256, 0, stream>>>(Wv, Wqkv_bf + (size_t)5120*4096, n8);
    n8 = 4096*4096/8;
    cvt_kernel<<<(n8+255)/256, 256, 0, stream>>>(Wo, Wo_bf, n8);
  }
  setup_kernel<<<(T_SEQ*64 + 255)/256, 256, 0, stream>>>(bq, bk, bv, pos, bqkv, cost, sint);

  // QKV projection: [2048,6144] — 256x192 tiles, grid 32x8 = 256 blocks (full fill)
  gemm_qkv<<<dim3(6144/192, 2048/256), 512, 0, stream>>>(hs_bf, Wqkv_bf, bqkv, qkv, 4096, 6144);
  // RoPE on q,k
  rope_kernel<<<(T_SEQ*40*64)/256, 256, 0, stream>>>(qkv, cost, sint);
  // attention
  attn_kernel<<<1024, 256, 0, stream>>>(qkv, attn_b);
  // output projection: [2048,4096] — 256x128 tiles, grid 32x8 = 256 blocks (full fill)
  gemm_km<<<dim3(4096/128, 2048/256), 512, 0, stream>>>(attn_b, Wo_bf, bo, out, 4096, 4096);
}